// Round 1
// baseline (1976.479 us; speedup 1.0000x reference)
//
#include <hip/hip_runtime.h>
#include <math.h>

// Problem constants (match reference)
#define B_ 4
#define L_ 2048
#define H_ 16
#define D_ 64
#define M_ 128
#define TC_ 64              // chunk length
#define NC_ (L_ / TC_)      // 32 chunks
#define EPSK 1e-6f
#define DATA_SCALE 0.35355339059327379f  // 64^{-1/4}
#define RATIO 0.08838834764831845f       // 128^{-1/2}

// ---- order-preserving float<->uint for atomic max ----
__device__ __forceinline__ unsigned enc_f(float f) {
    unsigned u = __float_as_uint(f);
    return (u & 0x80000000u) ? ~u : (u | 0x80000000u);
}
__device__ __forceinline__ float dec_f(unsigned u) {
    unsigned b = (u & 0x80000000u) ? (u ^ 0x80000000u) : ~u;
    return __uint_as_float(b);
}

// zero the 64 per-(b,h) max slots every call (ws is re-poisoned each launch)
__global__ void init_mx(unsigned* __restrict__ mx) {
    if (threadIdx.x < B_ * H_) mx[threadIdx.x] = 0u;  // < enc of any finite float
}

// K features pass 1: per (b,l,h) row compute data_dash, diag; store (dd - diag);
// atomic-max raw dd per (b,h).
__global__ void k_feat1(const float* __restrict__ k, const float* __restrict__ proj,
                        float* __restrict__ ktv, unsigned* __restrict__ mxk) {
    int row = blockIdx.x;            // ((b*L + l)*H + h)
    int h = row % H_;
    int b = row / (L_ * H_);
    int tid = threadIdx.x;           // 128 threads, one per m
    __shared__ float kk[D_];
    __shared__ float red[M_];
    const float* krow = k + (size_t)row * D_;
    if (tid < D_) kk[tid] = DATA_SCALE * krow[tid];
    __syncthreads();
    float dd = 0.f, diag = 0.f;
    const float* pr = proj + tid * D_;
#pragma unroll 8
    for (int d = 0; d < D_; d++) { float kv = kk[d]; dd += kv * pr[d]; diag += kv * kv; }
    diag *= 0.5f;
    ktv[(size_t)row * M_ + tid] = dd - diag;
    red[tid] = dd;
    __syncthreads();
    for (int s = 64; s > 0; s >>= 1) {
        if (tid < s) red[tid] = fmaxf(red[tid], red[tid + s]);
        __syncthreads();
    }
    if (tid == 0) atomicMax(&mxk[b * H_ + h], enc_f(red[0]));
}

// K features pass 2: elementwise kp = ratio*(exp(t - mx[b,h]) + eps), in place.
__global__ void k_exp_kernel(float* __restrict__ ktv, const unsigned* __restrict__ mxk) {
    size_t idx = (size_t)blockIdx.x * blockDim.x + threadIdx.x;  // B*L*H*M total
    int b = (int)(idx / ((size_t)L_ * H_ * M_));
    int h = (int)((idx / M_) % H_);
    float mx = dec_f(mxk[b * H_ + h]);
    float t = ktv[idx];
    ktv[idx] = RATIO * (expf(t - mx) + EPSK);
}

// Q features: per-row max over M only -> single pass.
__global__ void q_feat(const float* __restrict__ q, const float* __restrict__ proj,
                       float* __restrict__ qp) {
    int row = blockIdx.x;
    int tid = threadIdx.x;           // 128
    __shared__ float qq[D_];
    __shared__ float red[M_];
    const float* qrow = q + (size_t)row * D_;
    if (tid < D_) qq[tid] = DATA_SCALE * qrow[tid];
    __syncthreads();
    float dd = 0.f, diag = 0.f;
    const float* pr = proj + tid * D_;
#pragma unroll 8
    for (int d = 0; d < D_; d++) { float v = qq[d]; dd += v * pr[d]; diag += v * v; }
    diag *= 0.5f;
    red[tid] = dd;
    __syncthreads();
    for (int s = 64; s > 0; s >>= 1) {
        if (tid < s) red[tid] = fmaxf(red[tid], red[tid + s]);
        __syncthreads();
    }
    float mx = red[0];
    qp[(size_t)row * M_ + tid] = RATIO * (expf(dd - diag - mx) + EPSK);
}

// Per-chunk sums: S_c[m,d] = sum_{tau in chunk} kp[tau,m]*v[tau,d]; ds_c[m] = sum kp.
__global__ __launch_bounds__(256) void chunk_sum(const float* __restrict__ kp,
                                                 const float* __restrict__ v,
                                                 float* __restrict__ S,
                                                 float* __restrict__ ds) {
    int blk = blockIdx.x;            // (b*H + h)*NC + c
    int c = blk % NC_;
    int bh = blk / NC_;
    int h = bh % H_;
    int b = bh / H_;
    int tid = threadIdx.x;           // 256
    __shared__ float kl[M_];
    __shared__ float vl[D_];
    float acc[32];
#pragma unroll
    for (int i = 0; i < 32; i++) acc[i] = 0.f;
    float dsum = 0.f;
    int l0 = c * TC_;
    for (int tau = 0; tau < TC_; tau++) {
        int l = l0 + tau;
        size_t kbase = ((size_t)(b * L_ + l) * H_ + h) * M_;
        size_t vbase = ((size_t)(b * L_ + l) * H_ + h) * D_;
        if (tid < M_) kl[tid] = kp[kbase + tid];
        else if (tid < M_ + D_) vl[tid - M_] = v[vbase + tid - M_];
        __syncthreads();
#pragma unroll
        for (int i = 0; i < 32; i++) {
            int e = tid + 256 * i;
            acc[i] += kl[e >> 6] * vl[e & 63];
        }
        if (tid < M_) dsum += kl[tid];
        __syncthreads();
    }
    size_t sbase = (size_t)blk * (M_ * D_);
#pragma unroll
    for (int i = 0; i < 32; i++) S[sbase + tid + 256 * i] = acc[i];
    if (tid < M_) ds[(size_t)blk * M_ + tid] = dsum;
}

// Exclusive prefix over chunks, in place. Parallel over elements.
__global__ void prefix_S(float* __restrict__ S) {
    int blk = blockIdx.x;            // bh*32 + slice
    int slice = blk % 32;
    int bh = blk / 32;
    int e = slice * 256 + threadIdx.x;       // 0..8191
    size_t base = (size_t)bh * NC_ * (M_ * D_) + e;
    float carry = 0.f;
    for (int c = 0; c < NC_; c++) {
        size_t a = base + (size_t)c * (M_ * D_);
        float val = S[a];
        S[a] = carry;
        carry += val;
    }
}
__global__ void prefix_D(float* __restrict__ ds) {
    int bh = blockIdx.x;             // 64
    int m = threadIdx.x;             // 128
    size_t base = (size_t)bh * NC_ * M_ + m;
    float carry = 0.f;
    for (int c = 0; c < NC_; c++) {
        size_t a = base + (size_t)c * M_;
        float val = ds[a];
        ds[a] = carry;
        carry += val;
    }
}

// Main: out_t = (qp_t . S_prev + sum_{tau<=t} (qp_t.kp_tau) v_tau) / den_t
__global__ __launch_bounds__(256) void attn_kernel(
    const float* __restrict__ qp, const float* __restrict__ kp,
    const float* __restrict__ v, const float* __restrict__ Sp,
    const float* __restrict__ dp, float* __restrict__ out) {
    int blk = blockIdx.x;            // (b*H + h)*NC + c
    int c = blk % NC_;
    int bh = blk / NC_;
    int h = bh % H_;
    int b = bh / H_;
    int tid = threadIdx.x;           // 256
    int t = tid >> 2;                // query row in chunk (0..63)
    int sub = tid & 3;               // d-quarter
    int d0 = sub * 16;
    int l0 = c * TC_;

    __shared__ __align__(16) float qs[TC_][M_ + 4];  // 64 x 132 (pad vs bank conflicts)
    __shared__ __align__(16) float Bb[6144];         // staging: S_prev halves / ks+vs halves

    // load qp tile (64 x 128)
#pragma unroll
    for (int i = 0; i < 32; i++) {
        int e = tid + 256 * i;
        int tt = e >> 7, m = e & 127;
        qs[tt][m] = qp[((size_t)(b * L_ + l0 + tt) * H_ + h) * M_ + m];
    }
    __syncthreads();

    float acc[16];
#pragma unroll
    for (int j = 0; j < 16; j++) acc[j] = 0.f;

    // den contribution from d_prev (each sub handles a contiguous m-quarter)
    float den;
    {
        const float* dprev = dp + (size_t)blk * M_;
        float dpp = 0.f;
#pragma unroll
        for (int mi = 0; mi < 8; mi++) {
            float4 qv = *(const float4*)&qs[t][sub * 32 + mi * 4];
            float4 dv = *(const float4*)&dprev[sub * 32 + mi * 4];
            dpp += qv.x * dv.x + qv.y * dv.y + qv.z * dv.z + qv.w * dv.w;
        }
        dpp += __shfl_xor(dpp, 1, 64);
        dpp += __shfl_xor(dpp, 2, 64);
        den = dpp;
    }

    // phase 1: acc += qp_row . S_prev   (two m-halves of 64 staged in Bb)
    {
        size_t sbase = (size_t)blk * (M_ * D_);
        for (int mh = 0; mh < 2; mh++) {
#pragma unroll
            for (int i = 0; i < 16; i++) {
                int e = tid + 256 * i;  // 4096 elements
                Bb[e] = Sp[sbase + mh * 4096 + e];
            }
            __syncthreads();
            for (int ml = 0; ml < 64; ml++) {
                float qv = qs[t][mh * 64 + ml];
                const float4* srow = (const float4*)&Bb[ml * 64 + d0];
                float4 s0 = srow[0], s1 = srow[1], s2 = srow[2], s3 = srow[3];
                acc[0] += qv * s0.x; acc[1] += qv * s0.y; acc[2] += qv * s0.z; acc[3] += qv * s0.w;
                acc[4] += qv * s1.x; acc[5] += qv * s1.y; acc[6] += qv * s1.z; acc[7] += qv * s1.w;
                acc[8] += qv * s2.x; acc[9] += qv * s2.y; acc[10] += qv * s2.z; acc[11] += qv * s2.w;
                acc[12] += qv * s3.x; acc[13] += qv * s3.y; acc[14] += qv * s3.z; acc[15] += qv * s3.w;
            }
            __syncthreads();
        }
    }

    // phase 2: intra-chunk causal, two tau-halves of 32 (ks 32x128 + vs 32x64 in Bb)
    for (int hc = 0; hc < 2; hc++) {
#pragma unroll
        for (int i = 0; i < 16; i++) {
            int e = tid + 256 * i;  // 4096
            int tl = e >> 7, m = e & 127;
            Bb[e] = kp[((size_t)(b * L_ + l0 + hc * 32 + tl) * H_ + h) * M_ + m];
        }
#pragma unroll
        for (int i = 0; i < 8; i++) {
            int e = tid + 256 * i;  // 2048
            int tl = e >> 6, d = e & 63;
            Bb[4096 + e] = v[((size_t)(b * L_ + l0 + hc * 32 + tl) * H_ + h) * D_ + d];
        }
        __syncthreads();
        for (int tlb = 0; tlb < 32; tlb += 4) {
            // wave-uniform early-out: all 16 rows of this wave are below tau group
            if (hc * 32 + tlb > (t | 15)) break;
            float ap[4] = {0.f, 0.f, 0.f, 0.f};
            const float4* k0 = (const float4*)&Bb[(tlb + 0) * 128 + sub * 32];
            const float4* k1 = (const float4*)&Bb[(tlb + 1) * 128 + sub * 32];
            const float4* k2 = (const float4*)&Bb[(tlb + 2) * 128 + sub * 32];
            const float4* k3 = (const float4*)&Bb[(tlb + 3) * 128 + sub * 32];
#pragma unroll
            for (int mi = 0; mi < 8; mi++) {
                float4 qv = *(const float4*)&qs[t][sub * 32 + mi * 4];
                float4 b0 = k0[mi], b1 = k1[mi], b2 = k2[mi], b3 = k3[mi];
                ap[0] += qv.x * b0.x + qv.y * b0.y + qv.z * b0.z + qv.w * b0.w;
                ap[1] += qv.x * b1.x + qv.y * b1.y + qv.z * b1.z + qv.w * b1.w;
                ap[2] += qv.x * b2.x + qv.y * b2.y + qv.z * b2.z + qv.w * b2.w;
                ap[3] += qv.x * b3.x + qv.y * b3.y + qv.z * b3.z + qv.w * b3.w;
            }
#pragma unroll
            for (int u = 0; u < 4; u++) {
                ap[u] += __shfl_xor(ap[u], 1, 64);
                ap[u] += __shfl_xor(ap[u], 2, 64);
            }
#pragma unroll
            for (int u = 0; u < 4; u++) {
                int tau = hc * 32 + tlb + u;
                if (tau <= t) {
                    den += ap[u];
                    const float4* vrow = (const float4*)&Bb[4096 + (tlb + u) * 64 + d0];
                    float4 v0 = vrow[0], v1 = vrow[1], v2 = vrow[2], v3 = vrow[3];
                    float a = ap[u];
                    acc[0] += a * v0.x; acc[1] += a * v0.y; acc[2] += a * v0.z; acc[3] += a * v0.w;
                    acc[4] += a * v1.x; acc[5] += a * v1.y; acc[6] += a * v1.z; acc[7] += a * v1.w;
                    acc[8] += a * v2.x; acc[9] += a * v2.y; acc[10] += a * v2.z; acc[11] += a * v2.w;
                    acc[12] += a * v3.x; acc[13] += a * v3.y; acc[14] += a * v3.z; acc[15] += a * v3.w;
                }
            }
        }
        __syncthreads();
    }

    // write out / den
    float inv = 1.0f / den;
    size_t obase = ((size_t)(b * L_ + l0 + t) * H_ + h) * D_ + d0;
    float4* o = (float4*)(out + obase);
    float4 r0 = {acc[0] * inv, acc[1] * inv, acc[2] * inv, acc[3] * inv};
    float4 r1 = {acc[4] * inv, acc[5] * inv, acc[6] * inv, acc[7] * inv};
    float4 r2 = {acc[8] * inv, acc[9] * inv, acc[10] * inv, acc[11] * inv};
    float4 r3 = {acc[12] * inv, acc[13] * inv, acc[14] * inv, acc[15] * inv};
    o[0] = r0; o[1] = r1; o[2] = r2; o[3] = r3;
}

extern "C" void kernel_launch(void* const* d_in, const int* in_sizes, int n_in,
                              void* d_out, int out_size, void* d_ws, size_t ws_size,
                              hipStream_t stream) {
    const float* q = (const float*)d_in[0];
    const float* k = (const float*)d_in[1];
    const float* v = (const float*)d_in[2];
    const float* proj = (const float*)d_in[3];
    float* out = (float*)d_out;
    float* ws = (float*)d_ws;

    // workspace layout (floats)
    const size_t N_FEAT = (size_t)B_ * L_ * H_ * M_;   // 16,777,216
    float* qp = ws;
    float* kp = ws + N_FEAT;
    float* S = ws + 2 * N_FEAT;                        // B*H*NC*M*D = 16,777,216
    float* ds = ws + 3 * N_FEAT;                       // B*H*NC*M = 262,144
    unsigned* mx = (unsigned*)(ws + 3 * N_FEAT + (size_t)B_ * H_ * NC_ * M_);

    hipLaunchKernelGGL(init_mx, dim3(1), dim3(64), 0, stream, mx);
    hipLaunchKernelGGL(k_feat1, dim3(B_ * L_ * H_), dim3(128), 0, stream, k, proj, kp, mx);
    hipLaunchKernelGGL(k_exp_kernel, dim3((unsigned)(N_FEAT / 256)), dim3(256), 0, stream, kp, mx);
    hipLaunchKernelGGL(q_feat, dim3(B_ * L_ * H_), dim3(128), 0, stream, q, proj, qp);
    hipLaunchKernelGGL(chunk_sum, dim3(B_ * H_ * NC_), dim3(256), 0, stream, kp, v, S, ds);
    hipLaunchKernelGGL(prefix_S, dim3(B_ * H_ * 32), dim3(256), 0, stream, S);
    hipLaunchKernelGGL(prefix_D, dim3(B_ * H_), dim3(128), 0, stream, ds);
    hipLaunchKernelGGL(attn_kernel, dim3(B_ * H_ * NC_), dim3(256), 0, stream,
                       qp, kp, v, S, ds, out);
}

// Round 2
// 482.204 us; speedup vs baseline: 4.0988x; 4.0988x over previous
//
#include <hip/hip_runtime.h>
#include <math.h>

// Problem constants (match reference)
#define B_ 4
#define L_ 2048
#define H_ 16
#define D_ 64
#define M_ 128
#define TC_ 64              // chunk length
#define NC_ (L_ / TC_)      // 32 chunks
#define EPSK 1e-6f
#define DATA_SCALE 0.35355339059327379f  // 64^{-1/4}
#define RATIO 0.08838834764831845f       // 128^{-1/2}

// ---- order-preserving float<->uint for atomic max ----
__device__ __forceinline__ unsigned enc_f(float f) {
    unsigned u = __float_as_uint(f);
    return (u & 0x80000000u) ? ~u : (u | 0x80000000u);
}
__device__ __forceinline__ float dec_f(unsigned u) {
    unsigned b = (u & 0x80000000u) ? (u ^ 0x80000000u) : ~u;
    return __uint_as_float(b);
}

// zero the 64 per-(b,h) max slots every call (ws is re-poisoned each launch)
__global__ void init_mx(unsigned* __restrict__ mx) {
    if (threadIdx.x < B_ * H_) mx[threadIdx.x] = 0u;  // < enc of any finite float
}

// ---------------------------------------------------------------------------
// Feature GEMM: per block, 64 contiguous (b,l,h) rows.
//   data_dash[r][m] = sum_d (scale*data[r][d]) * proj[m][d]
//   diag[r] = 0.5 * sum_d (scale*data[r][d])^2
// IS_Q: out = ratio*(exp(dd - diag - rowmax) + eps)          (row max over m)
// !IS_Q: out = dd - diag; atomic-max raw dd per (b,h) for the later exp pass.
// LDS: projT staged 64x132 (pad 132 keeps float4 reads conflict-free),
//      dataT 64x68. One-time 8-way conflicts on the transposing stores are
//      negligible vs the 64x32-FMA main loop (VALU-bound by design).
// ---------------------------------------------------------------------------
template <bool IS_Q>
__global__ __launch_bounds__(256) void feat_gemm(const float* __restrict__ data,
                                                 const float* __restrict__ proj,
                                                 float* __restrict__ outp,
                                                 unsigned* __restrict__ mxk) {
    __shared__ float pt[D_][132];   // projT, padded: bank(4d+m), float4-aligned
    __shared__ float dt[D_][68];    // dataT (scaled), padded
    __shared__ float diag_s[64];
    __shared__ float rowmax_l[64];
    int tid = threadIdx.x;
    size_t fr0 = (size_t)blockIdx.x * 64;   // first flat row ((b*L+l)*H+h)

    // stage projT (128x64 -> [d][m]); coalesced float4 global reads
    const float4* p4 = (const float4*)proj;
#pragma unroll
    for (int i = 0; i < 8; i++) {
        int e = tid + 256 * i;          // 0..2047
        int m = e >> 4;
        int d0 = (e & 15) * 4;
        float4 v = p4[e];
        pt[d0 + 0][m] = v.x; pt[d0 + 1][m] = v.y;
        pt[d0 + 2][m] = v.z; pt[d0 + 3][m] = v.w;
    }
    // stage dataT scaled (64 rows x 64 d, contiguous in global)
    const float4* g4 = (const float4*)(data + fr0 * D_);
#pragma unroll
    for (int i = 0; i < 4; i++) {
        int e = tid + 256 * i;          // 0..1023
        int r = e >> 4;
        int d0 = (e & 15) * 4;
        float4 v = g4[e];
        dt[d0 + 0][r] = DATA_SCALE * v.x; dt[d0 + 1][r] = DATA_SCALE * v.y;
        dt[d0 + 2][r] = DATA_SCALE * v.z; dt[d0 + 3][r] = DATA_SCALE * v.w;
    }
    __syncthreads();

    // diag: 4 threads per row, 16 d each, shfl-combine
    {
        int r = tid >> 2, dq = tid & 3;
        float s = 0.f;
#pragma unroll
        for (int dd = 0; dd < 16; dd++) { float x = dt[dq * 16 + dd][r]; s += x * x; }
        s += __shfl_xor(s, 1, 64);
        s += __shfl_xor(s, 2, 64);
        if (dq == 0) diag_s[r] = 0.5f * s;
    }
    __syncthreads();

    // micro-kernel: thread = (rg, mg) -> rows r0..r0+7, cols m0..m0+3
    int mg = tid & 31, rg = tid >> 5;
    int m0 = mg * 4, r0 = rg * 8;
    float acc[8][4];
#pragma unroll
    for (int ri = 0; ri < 8; ri++)
#pragma unroll
        for (int mj = 0; mj < 4; mj++) acc[ri][mj] = 0.f;

    for (int d = 0; d < D_; d++) {
        float4 pv = *(const float4*)&pt[d][m0];
        float4 ra = *(const float4*)&dt[d][r0];
        float4 rb = *(const float4*)&dt[d][r0 + 4];
        float rr[8] = {ra.x, ra.y, ra.z, ra.w, rb.x, rb.y, rb.z, rb.w};
#pragma unroll
        for (int ri = 0; ri < 8; ri++) {
            acc[ri][0] += rr[ri] * pv.x;
            acc[ri][1] += rr[ri] * pv.y;
            acc[ri][2] += rr[ri] * pv.z;
            acc[ri][3] += rr[ri] * pv.w;
        }
    }

    // per-row max of raw data_dash across the 32 mg lanes
    float rmax[8];
#pragma unroll
    for (int ri = 0; ri < 8; ri++) {
        float m = fmaxf(fmaxf(acc[ri][0], acc[ri][1]), fmaxf(acc[ri][2], acc[ri][3]));
        m = fmaxf(m, __shfl_xor(m, 1, 64));
        m = fmaxf(m, __shfl_xor(m, 2, 64));
        m = fmaxf(m, __shfl_xor(m, 4, 64));
        m = fmaxf(m, __shfl_xor(m, 8, 64));
        m = fmaxf(m, __shfl_xor(m, 16, 64));
        rmax[ri] = m;
    }

    if (IS_Q) {
#pragma unroll
        for (int ri = 0; ri < 8; ri++) {
            float dg = diag_s[r0 + ri];
            float mx = rmax[ri];
            float4 o;
            o.x = RATIO * (expf(acc[ri][0] - dg - mx) + EPSK);
            o.y = RATIO * (expf(acc[ri][1] - dg - mx) + EPSK);
            o.z = RATIO * (expf(acc[ri][2] - dg - mx) + EPSK);
            o.w = RATIO * (expf(acc[ri][3] - dg - mx) + EPSK);
            *(float4*)&outp[(fr0 + r0 + ri) * M_ + m0] = o;
        }
    } else {
#pragma unroll
        for (int ri = 0; ri < 8; ri++) {
            float dg = diag_s[r0 + ri];
            float4 o = {acc[ri][0] - dg, acc[ri][1] - dg, acc[ri][2] - dg, acc[ri][3] - dg};
            *(float4*)&outp[(fr0 + r0 + ri) * M_ + m0] = o;
        }
        if (mg == 0) {
#pragma unroll
            for (int ri = 0; ri < 8; ri++) rowmax_l[r0 + ri] = rmax[ri];
        }
        __syncthreads();
        // rows cycle h every 16 (h is the fastest axis of the flat row index)
        if (tid < 16) {
            float m4 = fmaxf(fmaxf(rowmax_l[tid], rowmax_l[tid + 16]),
                             fmaxf(rowmax_l[tid + 32], rowmax_l[tid + 48]));
            int b = (int)(blockIdx.x >> 9);   // 512 blocks per batch
            atomicMax(&mxk[b * H_ + tid], enc_f(m4));
        }
    }
}

// K features pass 2: elementwise kp = ratio*(exp(t - mx[b,h]) + eps), float4.
__global__ void k_exp_kernel(float4* __restrict__ ktv, const unsigned* __restrict__ mxk) {
    size_t idx = (size_t)blockIdx.x * blockDim.x + threadIdx.x;  // N_FEAT/4
    size_t fidx = idx * 4;
    int b = (int)(fidx >> 22);          // / (L*H*M)
    int h = (int)((fidx >> 7) & 15);    // (/M) % H
    float mx = dec_f(mxk[b * H_ + h]);
    float4 t = ktv[idx];
    float4 o;
    o.x = RATIO * (expf(t.x - mx) + EPSK);
    o.y = RATIO * (expf(t.y - mx) + EPSK);
    o.z = RATIO * (expf(t.z - mx) + EPSK);
    o.w = RATIO * (expf(t.w - mx) + EPSK);
    ktv[idx] = o;
}

// Per-chunk sums: S_c[m,d] = sum_{tau in chunk} kp[tau,m]*v[tau,d]; ds_c[m] = sum kp.
__global__ __launch_bounds__(256) void chunk_sum(const float* __restrict__ kp,
                                                 const float* __restrict__ v,
                                                 float* __restrict__ S,
                                                 float* __restrict__ ds) {
    int blk = blockIdx.x;            // (b*H + h)*NC + c
    int c = blk % NC_;
    int bh = blk / NC_;
    int h = bh % H_;
    int b = bh / H_;
    int tid = threadIdx.x;           // 256
    __shared__ float kl[M_];
    __shared__ float vl[D_];
    float acc[32];
#pragma unroll
    for (int i = 0; i < 32; i++) acc[i] = 0.f;
    float dsum = 0.f;
    int l0 = c * TC_;
    for (int tau = 0; tau < TC_; tau++) {
        int l = l0 + tau;
        size_t kbase = ((size_t)(b * L_ + l) * H_ + h) * M_;
        size_t vbase = ((size_t)(b * L_ + l) * H_ + h) * D_;
        if (tid < M_) kl[tid] = kp[kbase + tid];
        else if (tid < M_ + D_) vl[tid - M_] = v[vbase + tid - M_];
        __syncthreads();
#pragma unroll
        for (int i = 0; i < 32; i++) {
            int e = tid + 256 * i;
            acc[i] += kl[e >> 6] * vl[e & 63];
        }
        if (tid < M_) dsum += kl[tid];
        __syncthreads();
    }
    size_t sbase = (size_t)blk * (M_ * D_);
#pragma unroll
    for (int i = 0; i < 32; i++) S[sbase + tid + 256 * i] = acc[i];
    if (tid < M_) ds[(size_t)blk * M_ + tid] = dsum;
}

// Exclusive prefix over chunks, in place. Parallel over elements.
__global__ void prefix_S(float* __restrict__ S) {
    int blk = blockIdx.x;            // bh*32 + slice
    int slice = blk % 32;
    int bh = blk / 32;
    int e = slice * 256 + threadIdx.x;       // 0..8191
    size_t base = (size_t)bh * NC_ * (M_ * D_) + e;
    float carry = 0.f;
    for (int c = 0; c < NC_; c++) {
        size_t a = base + (size_t)c * (M_ * D_);
        float val = S[a];
        S[a] = carry;
        carry += val;
    }
}
__global__ void prefix_D(float* __restrict__ ds) {
    int bh = blockIdx.x;             // 64
    int m = threadIdx.x;             // 128
    size_t base = (size_t)bh * NC_ * M_ + m;
    float carry = 0.f;
    for (int c = 0; c < NC_; c++) {
        size_t a = base + (size_t)c * M_;
        float val = ds[a];
        ds[a] = carry;
        carry += val;
    }
}

// Main: out_t = (qp_t . S_prev + sum_{tau<=t} (qp_t.kp_tau) v_tau) / den_t
__global__ __launch_bounds__(256) void attn_kernel(
    const float* __restrict__ qp, const float* __restrict__ kp,
    const float* __restrict__ v, const float* __restrict__ Sp,
    const float* __restrict__ dp, float* __restrict__ out) {
    int blk = blockIdx.x;            // (b*H + h)*NC + c
    int c = blk % NC_;
    int bh = blk / NC_;
    int h = bh % H_;
    int b = bh / H_;
    int tid = threadIdx.x;           // 256
    int t = tid >> 2;                // query row in chunk (0..63)
    int sub = tid & 3;               // d-quarter
    int d0 = sub * 16;
    int l0 = c * TC_;

    __shared__ __align__(16) float qs[TC_][M_ + 4];  // 64 x 132 (pad vs bank conflicts)
    __shared__ __align__(16) float Bb[6144];         // staging: S_prev halves / ks+vs halves

    // load qp tile (64 x 128)
#pragma unroll
    for (int i = 0; i < 32; i++) {
        int e = tid + 256 * i;
        int tt = e >> 7, m = e & 127;
        qs[tt][m] = qp[((size_t)(b * L_ + l0 + tt) * H_ + h) * M_ + m];
    }
    __syncthreads();

    float acc[16];
#pragma unroll
    for (int j = 0; j < 16; j++) acc[j] = 0.f;

    // den contribution from d_prev (each sub handles a contiguous m-quarter)
    float den;
    {
        const float* dprev = dp + (size_t)blk * M_;
        float dpp = 0.f;
#pragma unroll
        for (int mi = 0; mi < 8; mi++) {
            float4 qv = *(const float4*)&qs[t][sub * 32 + mi * 4];
            float4 dv = *(const float4*)&dprev[sub * 32 + mi * 4];
            dpp += qv.x * dv.x + qv.y * dv.y + qv.z * dv.z + qv.w * dv.w;
        }
        dpp += __shfl_xor(dpp, 1, 64);
        dpp += __shfl_xor(dpp, 2, 64);
        den = dpp;
    }

    // phase 1: acc += qp_row . S_prev   (two m-halves of 64 staged in Bb)
    {
        size_t sbase = (size_t)blk * (M_ * D_);
        for (int mh = 0; mh < 2; mh++) {
#pragma unroll
            for (int i = 0; i < 16; i++) {
                int e = tid + 256 * i;  // 4096 elements
                Bb[e] = Sp[sbase + mh * 4096 + e];
            }
            __syncthreads();
            for (int ml = 0; ml < 64; ml++) {
                float qv = qs[t][mh * 64 + ml];
                const float4* srow = (const float4*)&Bb[ml * 64 + d0];
                float4 s0 = srow[0], s1 = srow[1], s2 = srow[2], s3 = srow[3];
                acc[0] += qv * s0.x; acc[1] += qv * s0.y; acc[2] += qv * s0.z; acc[3] += qv * s0.w;
                acc[4] += qv * s1.x; acc[5] += qv * s1.y; acc[6] += qv * s1.z; acc[7] += qv * s1.w;
                acc[8] += qv * s2.x; acc[9] += qv * s2.y; acc[10] += qv * s2.z; acc[11] += qv * s2.w;
                acc[12] += qv * s3.x; acc[13] += qv * s3.y; acc[14] += qv * s3.z; acc[15] += qv * s3.w;
            }
            __syncthreads();
        }
    }

    // phase 2: intra-chunk causal, two tau-halves of 32 (ks 32x128 + vs 32x64 in Bb)
    for (int hc = 0; hc < 2; hc++) {
#pragma unroll
        for (int i = 0; i < 16; i++) {
            int e = tid + 256 * i;  // 4096
            int tl = e >> 7, m = e & 127;
            Bb[e] = kp[((size_t)(b * L_ + l0 + hc * 32 + tl) * H_ + h) * M_ + m];
        }
#pragma unroll
        for (int i = 0; i < 8; i++) {
            int e = tid + 256 * i;  // 2048
            int tl = e >> 6, d = e & 63;
            Bb[4096 + e] = v[((size_t)(b * L_ + l0 + hc * 32 + tl) * H_ + h) * D_ + d];
        }
        __syncthreads();
        for (int tlb = 0; tlb < 32; tlb += 4) {
            // wave-uniform early-out: all 16 rows of this wave are below tau group
            if (hc * 32 + tlb > (t | 15)) break;
            float ap[4] = {0.f, 0.f, 0.f, 0.f};
            const float4* k0 = (const float4*)&Bb[(tlb + 0) * 128 + sub * 32];
            const float4* k1 = (const float4*)&Bb[(tlb + 1) * 128 + sub * 32];
            const float4* k2 = (const float4*)&Bb[(tlb + 2) * 128 + sub * 32];
            const float4* k3 = (const float4*)&Bb[(tlb + 3) * 128 + sub * 32];
#pragma unroll
            for (int mi = 0; mi < 8; mi++) {
                float4 qv = *(const float4*)&qs[t][sub * 32 + mi * 4];
                float4 b0 = k0[mi], b1 = k1[mi], b2 = k2[mi], b3 = k3[mi];
                ap[0] += qv.x * b0.x + qv.y * b0.y + qv.z * b0.z + qv.w * b0.w;
                ap[1] += qv.x * b1.x + qv.y * b1.y + qv.z * b1.z + qv.w * b1.w;
                ap[2] += qv.x * b2.x + qv.y * b2.y + qv.z * b2.z + qv.w * b2.w;
                ap[3] += qv.x * b3.x + qv.y * b3.y + qv.z * b3.z + qv.w * b3.w;
            }
#pragma unroll
            for (int u = 0; u < 4; u++) {
                ap[u] += __shfl_xor(ap[u], 1, 64);
                ap[u] += __shfl_xor(ap[u], 2, 64);
            }
#pragma unroll
            for (int u = 0; u < 4; u++) {
                int tau = hc * 32 + tlb + u;
                if (tau <= t) {
                    den += ap[u];
                    const float4* vrow = (const float4*)&Bb[4096 + (tlb + u) * 64 + d0];
                    float4 v0 = vrow[0], v1 = vrow[1], v2 = vrow[2], v3 = vrow[3];
                    float a = ap[u];
                    acc[0] += a * v0.x; acc[1] += a * v0.y; acc[2] += a * v0.z; acc[3] += a * v0.w;
                    acc[4] += a * v1.x; acc[5] += a * v1.y; acc[6] += a * v1.z; acc[7] += a * v1.w;
                    acc[8] += a * v2.x; acc[9] += a * v2.y; acc[10] += a * v2.z; acc[11] += a * v2.w;
                    acc[12] += a * v3.x; acc[13] += a * v3.y; acc[14] += a * v3.z; acc[15] += a * v3.w;
                }
            }
        }
        __syncthreads();
    }

    // write out / den
    float inv = 1.0f / den;
    size_t obase = ((size_t)(b * L_ + l0 + t) * H_ + h) * D_ + d0;
    float4* o = (float4*)(out + obase);
    float4 r0 = {acc[0] * inv, acc[1] * inv, acc[2] * inv, acc[3] * inv};
    float4 r1 = {acc[4] * inv, acc[5] * inv, acc[6] * inv, acc[7] * inv};
    float4 r2 = {acc[8] * inv, acc[9] * inv, acc[10] * inv, acc[11] * inv};
    float4 r3 = {acc[12] * inv, acc[13] * inv, acc[14] * inv, acc[15] * inv};
    o[0] = r0; o[1] = r1; o[2] = r2; o[3] = r3;
}

extern "C" void kernel_launch(void* const* d_in, const int* in_sizes, int n_in,
                              void* d_out, int out_size, void* d_ws, size_t ws_size,
                              hipStream_t stream) {
    const float* q = (const float*)d_in[0];
    const float* k = (const float*)d_in[1];
    const float* v = (const float*)d_in[2];
    const float* proj = (const float*)d_in[3];
    float* out = (float*)d_out;
    float* ws = (float*)d_ws;

    // workspace layout (floats)
    const size_t N_FEAT = (size_t)B_ * L_ * H_ * M_;   // 16,777,216
    float* qp = ws;
    float* kp = ws + N_FEAT;
    float* S = ws + 2 * N_FEAT;                        // B*H*NC*M*D = 16,777,216
    float* ds = ws + 3 * N_FEAT;                       // B*H*NC*M = 262,144
    unsigned* mx = (unsigned*)(ws + 3 * N_FEAT + (size_t)B_ * H_ * NC_ * M_);

    const int ROW_TILES = B_ * L_ * H_ / 64;           // 2048

    hipLaunchKernelGGL(init_mx, dim3(1), dim3(64), 0, stream, mx);
    hipLaunchKernelGGL((feat_gemm<false>), dim3(ROW_TILES), dim3(256), 0, stream, k, proj, kp, mx);
    hipLaunchKernelGGL(k_exp_kernel, dim3((unsigned)(N_FEAT / 4 / 256)), dim3(256), 0, stream,
                       (float4*)kp, mx);
    hipLaunchKernelGGL((feat_gemm<true>), dim3(ROW_TILES), dim3(256), 0, stream, q, proj, qp, (unsigned*)nullptr);
    hipLaunchKernelGGL(chunk_sum, dim3(B_ * H_ * NC_), dim3(256), 0, stream, kp, v, S, ds);
    hipLaunchKernelGGL(prefix_S, dim3(B_ * H_ * 32), dim3(256), 0, stream, S);
    hipLaunchKernelGGL(prefix_D, dim3(B_ * H_), dim3(128), 0, stream, ds);
    hipLaunchKernelGGL(attn_kernel, dim3(B_ * H_ * NC_), dim3(256), 0, stream,
                       qp, kp, v, S, ds, out);
}

// Round 3
// 289.151 us; speedup vs baseline: 6.8354x; 1.6677x over previous
//
#include <hip/hip_runtime.h>
#include <math.h>

// Problem constants (match reference)
#define B_ 4
#define L_ 2048
#define H_ 16
#define D_ 64
#define M_ 128
#define TC_ 64              // chunk length
#define NC_ (L_ / TC_)      // 32 chunks
#define EPSK 1e-6f
#define DATA_SCALE 0.35355339059327379f  // 64^{-1/4}
#define RATIO 0.08838834764831845f       // 128^{-1/2}

typedef __bf16 bf16;
typedef bf16 bf16x4 __attribute__((ext_vector_type(4)));
typedef bf16 bf16x8 __attribute__((ext_vector_type(8)));
typedef float floatx4 __attribute__((ext_vector_type(4)));

__device__ __forceinline__ unsigned pk(bf16 a, bf16 b) {
    return (unsigned)__builtin_bit_cast(unsigned short, a) |
           ((unsigned)__builtin_bit_cast(unsigned short, b) << 16);
}

// ---- order-preserving float<->uint for atomic max ----
__device__ __forceinline__ unsigned enc_f(float f) {
    unsigned u = __float_as_uint(f);
    return (u & 0x80000000u) ? ~u : (u | 0x80000000u);
}
__device__ __forceinline__ float dec_f(unsigned u) {
    unsigned b = (u & 0x80000000u) ? (u ^ 0x80000000u) : ~u;
    return __uint_as_float(b);
}

__global__ void init_mx(unsigned* __restrict__ mx) {
    if (threadIdx.x < B_ * H_) mx[threadIdx.x] = 0u;
}

// ---------------------------------------------------------------------------
// Feature GEMM (fp32 VALU): per block, 64 contiguous (b,l,h) rows.
// IS_Q: out = bf16( ratio*(exp(dd - diag - rowmax) + eps) )
// !IS_Q: out = fp32(dd - diag); atomic-max raw dd per (b,h).
// ---------------------------------------------------------------------------
template <bool IS_Q>
__global__ __launch_bounds__(256) void feat_gemm(const float* __restrict__ data,
                                                 const float* __restrict__ proj,
                                                 void* __restrict__ outp,
                                                 unsigned* __restrict__ mxk) {
    __shared__ float pt[D_][132];
    __shared__ float dt[D_][68];
    __shared__ float diag_s[64];
    __shared__ float rowmax_l[64];
    int tid = threadIdx.x;
    size_t fr0 = (size_t)blockIdx.x * 64;

    const float4* p4 = (const float4*)proj;
#pragma unroll
    for (int i = 0; i < 8; i++) {
        int e = tid + 256 * i;
        int m = e >> 4;
        int d0 = (e & 15) * 4;
        float4 v = p4[e];
        pt[d0 + 0][m] = v.x; pt[d0 + 1][m] = v.y;
        pt[d0 + 2][m] = v.z; pt[d0 + 3][m] = v.w;
    }
    const float4* g4 = (const float4*)(data + fr0 * D_);
#pragma unroll
    for (int i = 0; i < 4; i++) {
        int e = tid + 256 * i;
        int r = e >> 4;
        int d0 = (e & 15) * 4;
        float4 v = g4[e];
        dt[d0 + 0][r] = DATA_SCALE * v.x; dt[d0 + 1][r] = DATA_SCALE * v.y;
        dt[d0 + 2][r] = DATA_SCALE * v.z; dt[d0 + 3][r] = DATA_SCALE * v.w;
    }
    __syncthreads();

    {
        int r = tid >> 2, dq = tid & 3;
        float s = 0.f;
#pragma unroll
        for (int dd = 0; dd < 16; dd++) { float x = dt[dq * 16 + dd][r]; s += x * x; }
        s += __shfl_xor(s, 1, 64);
        s += __shfl_xor(s, 2, 64);
        if (dq == 0) diag_s[r] = 0.5f * s;
    }
    __syncthreads();

    int mg = tid & 31, rg = tid >> 5;
    int m0 = mg * 4, r0 = rg * 8;
    float acc[8][4];
#pragma unroll
    for (int ri = 0; ri < 8; ri++)
#pragma unroll
        for (int mj = 0; mj < 4; mj++) acc[ri][mj] = 0.f;

    for (int d = 0; d < D_; d++) {
        float4 pv = *(const float4*)&pt[d][m0];
        float4 ra = *(const float4*)&dt[d][r0];
        float4 rb = *(const float4*)&dt[d][r0 + 4];
        float rr[8] = {ra.x, ra.y, ra.z, ra.w, rb.x, rb.y, rb.z, rb.w};
#pragma unroll
        for (int ri = 0; ri < 8; ri++) {
            acc[ri][0] += rr[ri] * pv.x;
            acc[ri][1] += rr[ri] * pv.y;
            acc[ri][2] += rr[ri] * pv.z;
            acc[ri][3] += rr[ri] * pv.w;
        }
    }

    float rmax[8];
#pragma unroll
    for (int ri = 0; ri < 8; ri++) {
        float m = fmaxf(fmaxf(acc[ri][0], acc[ri][1]), fmaxf(acc[ri][2], acc[ri][3]));
        m = fmaxf(m, __shfl_xor(m, 1, 64));
        m = fmaxf(m, __shfl_xor(m, 2, 64));
        m = fmaxf(m, __shfl_xor(m, 4, 64));
        m = fmaxf(m, __shfl_xor(m, 8, 64));
        m = fmaxf(m, __shfl_xor(m, 16, 64));
        rmax[ri] = m;
    }

    if (IS_Q) {
        bf16* ob = (bf16*)outp;
#pragma unroll
        for (int ri = 0; ri < 8; ri++) {
            float dg = diag_s[r0 + ri];
            float mx = rmax[ri];
            bf16x4 o4;
            o4[0] = (bf16)(RATIO * (expf(acc[ri][0] - dg - mx) + EPSK));
            o4[1] = (bf16)(RATIO * (expf(acc[ri][1] - dg - mx) + EPSK));
            o4[2] = (bf16)(RATIO * (expf(acc[ri][2] - dg - mx) + EPSK));
            o4[3] = (bf16)(RATIO * (expf(acc[ri][3] - dg - mx) + EPSK));
            *(bf16x4*)(ob + (fr0 + r0 + ri) * M_ + m0) = o4;
        }
    } else {
        float* of = (float*)outp;
#pragma unroll
        for (int ri = 0; ri < 8; ri++) {
            float dg = diag_s[r0 + ri];
            float4 o = {acc[ri][0] - dg, acc[ri][1] - dg, acc[ri][2] - dg, acc[ri][3] - dg};
            *(float4*)&of[(fr0 + r0 + ri) * M_ + m0] = o;
        }
        if (mg == 0) {
#pragma unroll
            for (int ri = 0; ri < 8; ri++) rowmax_l[r0 + ri] = rmax[ri];
        }
        __syncthreads();
        if (tid < 16) {
            float m4 = fmaxf(fmaxf(rowmax_l[tid], rowmax_l[tid + 16]),
                             fmaxf(rowmax_l[tid + 32], rowmax_l[tid + 48]));
            int b = (int)(blockIdx.x >> 9);
            atomicMax(&mxk[b * H_ + tid], enc_f(m4));
        }
    }
}

// ---------------------------------------------------------------------------
// K exp + transpose: block = (b,h,c). Reads ktmp fp32 (dd-diag), applies
// exp with global (b,h) max, writes kp bf16 [b][l][h][m] and kpT bf16
// [b][h][m][l] (via LDS transpose).
// ---------------------------------------------------------------------------
__global__ __launch_bounds__(256) void k_exp_t(const float* __restrict__ ktmp,
                                               const unsigned* __restrict__ mxk,
                                               bf16* __restrict__ kp,
                                               bf16* __restrict__ kpT) {
    __shared__ __align__(16) bf16 kt[64 * 130];   // pad 130: transpose reads ~conflict-free
    int tid = threadIdx.x;
    int blk = blockIdx.x;
    int c = blk & 31, hh = (blk >> 5) & 15, b = blk >> 9;
    float mx = dec_f(mxk[b * H_ + hh]);
#pragma unroll
    for (int i = 0; i < 8; i++) {
        int ch = tid + 256 * i;          // 2048 float4 chunks (64 rows x 32)
        int row = ch >> 5, c4 = ch & 31;
        size_t gb = ((size_t)(b * L_ + c * 64 + row) * H_ + hh) * M_;
        float4 v = *(const float4*)(ktmp + gb + c4 * 4);
        bf16 e0 = (bf16)(RATIO * (expf(v.x - mx) + EPSK));
        bf16 e1 = (bf16)(RATIO * (expf(v.y - mx) + EPSK));
        bf16 e2 = (bf16)(RATIO * (expf(v.z - mx) + EPSK));
        bf16 e3 = (bf16)(RATIO * (expf(v.w - mx) + EPSK));
        bf16x4 o4; o4[0] = e0; o4[1] = e1; o4[2] = e2; o4[3] = e3;
        *(bf16x4*)(kp + gb + c4 * 4) = o4;
        unsigned* lp = (unsigned*)(kt + row * 130 + c4 * 4);
        lp[0] = pk(e0, e1); lp[1] = pk(e2, e3);
    }
    __syncthreads();
    size_t ob = (size_t)((b * H_ + hh) * M_) * (size_t)L_ + c * 64;
#pragma unroll
    for (int i = 0; i < 16; i++) {
        int e2 = tid + 256 * i;          // 4096 pairs
        int m = e2 >> 5, tau2 = (e2 & 31) * 2;
        *(unsigned*)(kpT + ob + (size_t)m * L_ + tau2) =
            pk(kt[tau2 * 130 + m], kt[(tau2 + 1) * 130 + m]);
    }
}

// ---------------------------------------------------------------------------
// V transpose: block = (b,h,c). v fp32 [b][l][h][d] -> vbT bf16 [b][h][d][l].
// ---------------------------------------------------------------------------
__global__ __launch_bounds__(256) void v_tr(const float* __restrict__ v,
                                            bf16* __restrict__ vbT) {
    __shared__ __align__(16) bf16 vt[64 * 66];
    int tid = threadIdx.x;
    int blk = blockIdx.x;
    int c = blk & 31, hh = (blk >> 5) & 15, b = blk >> 9;
#pragma unroll
    for (int i = 0; i < 4; i++) {
        int ch = tid + 256 * i;          // 1024 float4 chunks (64 rows x 16)
        int row = ch >> 4, c4 = ch & 15;
        size_t gb = ((size_t)(b * L_ + c * 64 + row) * H_ + hh) * D_;
        float4 x = *(const float4*)(v + gb + c4 * 4);
        unsigned* lp = (unsigned*)(vt + row * 66 + c4 * 4);
        lp[0] = pk((bf16)x.x, (bf16)x.y);
        lp[1] = pk((bf16)x.z, (bf16)x.w);
    }
    __syncthreads();
    size_t ob = (size_t)((b * H_ + hh) * D_) * (size_t)L_ + c * 64;
#pragma unroll
    for (int i = 0; i < 8; i++) {
        int e2 = tid + 256 * i;          // 2048 pairs
        int d = e2 >> 5, tau2 = (e2 & 31) * 2;
        *(unsigned*)(vbT + ob + (size_t)d * L_ + tau2) =
            pk(vt[tau2 * 66 + d], vt[(tau2 + 1) * 66 + d]);
    }
}

// ---------------------------------------------------------------------------
// Chunk sums via MFMA: S^T[d][m] = sum_tau v[tau][d]*kp[tau][m] (bf16 out),
// ds[m] = sum_tau kp[tau][m] (fp32). Block = (bh,c), 4 waves.
// ---------------------------------------------------------------------------
__global__ __launch_bounds__(256) void chunk_mfma(const bf16* __restrict__ kpT,
                                                  const bf16* __restrict__ vbT,
                                                  bf16* __restrict__ S,
                                                  float* __restrict__ ds) {
    __shared__ __align__(16) bf16 kT[128 * 64];   // [m][tau]
    __shared__ __align__(16) bf16 vT[64 * 64];    // [d][tau]
    int tid = threadIdx.x;
    int blk = blockIdx.x;
    int c = blk & 31, bh = blk >> 5;
    int l0 = c * 64;
#pragma unroll
    for (int i = 0; i < 4; i++) {
        int ch = tid + 256 * i;          // 1024 chunks (128 rows x 8)
        int m = ch >> 3, c8 = ch & 7;
        ((uint4*)kT)[ch] = ((const uint4*)kpT)[(((size_t)bh * M_ + m) * L_ + l0) / 8 + c8];
    }
#pragma unroll
    for (int i = 0; i < 2; i++) {
        int ch = tid + 256 * i;          // 512 chunks (64 rows x 8)
        int d = ch >> 3, c8 = ch & 7;
        ((uint4*)vT)[ch] = ((const uint4*)vbT)[(((size_t)bh * D_ + d) * L_ + l0) / 8 + c8];
    }
    __syncthreads();

    int w = tid >> 6, lane = tid & 63, lr = lane & 15, quad = lane >> 4;
    floatx4 acc[8];
#pragma unroll
    for (int tc = 0; tc < 8; tc++) acc[tc] = (floatx4){0.f, 0.f, 0.f, 0.f};
#pragma unroll
    for (int k0 = 0; k0 < 64; k0 += 32) {
        bf16x8 a = *(const bf16x8*)(vT + (16 * w + lr) * 64 + k0 + quad * 8);
#pragma unroll
        for (int tc = 0; tc < 8; tc++) {
            bf16x8 bb = *(const bf16x8*)(kT + (16 * tc + lr) * 64 + k0 + quad * 8);
            acc[tc] = __builtin_amdgcn_mfma_f32_16x16x32_bf16(a, bb, acc[tc], 0, 0, 0);
        }
    }
    size_t sb = (size_t)blk * (D_ * M_);
    int d0 = 16 * w + 4 * quad;
#pragma unroll
    for (int tc = 0; tc < 8; tc++)
#pragma unroll
        for (int reg = 0; reg < 4; reg++)
            S[sb + (size_t)(d0 + reg) * M_ + 16 * tc + lr] = (bf16)acc[tc][reg];

    // ds[m]: 2 threads per m, 32 taus each
    {
        int m = tid >> 1, half = tid & 1;
        const bf16x8* kr = (const bf16x8*)(kT + m * 64 + half * 32);
        float s = 0.f;
#pragma unroll
        for (int j = 0; j < 4; j++) {
            bf16x8 vv = kr[j];
#pragma unroll
            for (int e = 0; e < 8; e++) s += (float)vv[e];
        }
        s += __shfl_xor(s, 1, 64);
        if (!half) ds[(size_t)blk * M_ + m] = s;
    }
}

// Exclusive prefix over chunks, bf16 in place (fp32 carries), 2 elems/thread.
__global__ void prefix_S(unsigned* __restrict__ S) {
    int blk = blockIdx.x;
    int seg = blk & 15, bh = blk >> 4;
    int p = seg * 256 + threadIdx.x;            // 0..4095 uint pairs per chunk
    size_t base = (size_t)bh * NC_ * 4096 + p;
    float c0 = 0.f, c1 = 0.f;
    for (int c = 0; c < NC_; c++) {
        size_t a = base + (size_t)c * 4096;
        unsigned u = S[a];
        float f0 = (float)__builtin_bit_cast(bf16, (unsigned short)(u & 0xffffu));
        float f1 = (float)__builtin_bit_cast(bf16, (unsigned short)(u >> 16));
        S[a] = pk((bf16)c0, (bf16)c1);
        c0 += f0; c1 += f1;
    }
}

__global__ void prefix_D(float* __restrict__ ds) {
    int bh = blockIdx.x;
    int m = threadIdx.x;
    size_t base = (size_t)bh * NC_ * M_ + m;
    float carry = 0.f;
    for (int c = 0; c < NC_; c++) {
        size_t a = base + (size_t)c * M_;
        float val = ds[a];
        ds[a] = carry;
        carry += val;
    }
}

// ---------------------------------------------------------------------------
// Main attention via MFMA. Block = (bh,c), 4 waves; wave w owns t-rows
// 16w..16w+15. Phase1: Qp.S_prev (K=128). Phase2a: scores Qp.Kp^T (K=128),
// causal mask in C-regs, den row-reduce, bf16 round-trip through LDS.
// Phase2b: Sc.V (K=64). Out = acc/den.
// ---------------------------------------------------------------------------
__global__ __launch_bounds__(256) void attn_mfma(const bf16* __restrict__ qp,
                                                 const bf16* __restrict__ kp,
                                                 const bf16* __restrict__ vbT,
                                                 const bf16* __restrict__ Sp,
                                                 const float* __restrict__ dp,
                                                 float* __restrict__ out) {
    __shared__ __align__(16) bf16 qs[64 * 128];
    __shared__ __align__(16) bf16 ks[64 * 128];
    __shared__ __align__(16) bf16 spT[64 * 128];  // S_prev^T [d][m]
    __shared__ __align__(16) bf16 vT[64 * 64];    // [d][tau]
    __shared__ __align__(16) bf16 sc[64 * 64];    // masked scores [t][tau]
    __shared__ float dprevL[128];
    __shared__ float den0_l[64];
    __shared__ float densc_l[64];

    int tid = threadIdx.x;
    int blk = blockIdx.x;
    int c = blk & 31, bh = blk >> 5;
    int h = bh & 15, b = bh >> 4;
    int l0 = c * 64;

    // stage qs, ks (64x128 bf16 each)
#pragma unroll
    for (int i = 0; i < 4; i++) {
        int ch = tid + 256 * i;          // 1024 chunks (64 rows x 16)
        int row = ch >> 4, c8 = ch & 15;
        size_t gb = (((size_t)(b * L_ + l0 + row) * H_ + h) * M_) / 8;
        ((uint4*)qs)[ch] = ((const uint4*)qp)[gb + c8];
        ((uint4*)ks)[ch] = ((const uint4*)kp)[gb + c8];
    }
    // stage SpT (contiguous)
#pragma unroll
    for (int i = 0; i < 4; i++) {
        int ch = tid + 256 * i;
        ((uint4*)spT)[ch] = ((const uint4*)Sp)[(size_t)blk * 1024 + ch];
    }
    // stage vT + zero sc
    uint4 z; z.x = z.y = z.z = z.w = 0u;
#pragma unroll
    for (int i = 0; i < 2; i++) {
        int ch = tid + 256 * i;          // 512 chunks
        int d = ch >> 3, c8 = ch & 7;
        ((uint4*)vT)[ch] = ((const uint4*)vbT)[(((size_t)bh * D_ + d) * L_ + l0) / 8 + c8];
        ((uint4*)sc)[ch] = z;
    }
    if (tid < 128) dprevL[tid] = dp[(size_t)blk * M_ + tid];
    __syncthreads();

    // den0[t] = qp_t . dprev
    {
        int t = tid >> 2, p = tid & 3;
        const bf16* qrow = qs + t * 128 + p * 32;
        float s = 0.f;
#pragma unroll
        for (int i = 0; i < 32; i++) s += (float)qrow[i] * dprevL[p * 32 + i];
        s += __shfl_xor(s, 1, 64);
        s += __shfl_xor(s, 2, 64);
        if (p == 0) den0_l[t] = s;
    }

    int w = tid >> 6, lane = tid & 63, lr = lane & 15, quad = lane >> 4;
    const bf16* arow = qs + (16 * w + lr) * 128 + quad * 8;

    floatx4 acc[4];
#pragma unroll
    for (int tc = 0; tc < 4; tc++) acc[tc] = (floatx4){0.f, 0.f, 0.f, 0.f};

    // phase 1: Qp . S_prev
#pragma unroll
    for (int k0 = 0; k0 < 128; k0 += 32) {
        bf16x8 a = *(const bf16x8*)(arow + k0);
#pragma unroll
        for (int tc = 0; tc < 4; tc++) {
            bf16x8 bb = *(const bf16x8*)(spT + (16 * tc + lr) * 128 + k0 + quad * 8);
            acc[tc] = __builtin_amdgcn_mfma_f32_16x16x32_bf16(a, bb, acc[tc], 0, 0, 0);
        }
    }

    // phase 2a: scores (only tiles tc<=w needed; rest stays zero in sc)
    floatx4 acc2[4];
#pragma unroll
    for (int tc = 0; tc < 4; tc++) acc2[tc] = (floatx4){0.f, 0.f, 0.f, 0.f};
#pragma unroll
    for (int k0 = 0; k0 < 128; k0 += 32) {
        bf16x8 a = *(const bf16x8*)(arow + k0);
        for (int tc = 0; tc <= w; tc++) {
            bf16x8 bb = *(const bf16x8*)(ks + (16 * tc + lr) * 128 + k0 + quad * 8);
            acc2[tc] = __builtin_amdgcn_mfma_f32_16x16x32_bf16(a, bb, acc2[tc], 0, 0, 0);
        }
    }

    // mask + den partials + bf16 scores to LDS
    {
        float dsum[4] = {0.f, 0.f, 0.f, 0.f};
        int t0 = 16 * w + 4 * quad;
        for (int tc = 0; tc <= w; tc++) {
#pragma unroll
            for (int reg = 0; reg < 4; reg++) {
                int tg = t0 + reg, tau = 16 * tc + lr;
                float vv = acc2[tc][reg];
                if (tau > tg) vv = 0.f;
                dsum[reg] += vv;
                sc[tg * 64 + tau] = (bf16)vv;
            }
        }
#pragma unroll
        for (int reg = 0; reg < 4; reg++) {
            float s = dsum[reg];
            s += __shfl_xor(s, 1, 64);
            s += __shfl_xor(s, 2, 64);
            s += __shfl_xor(s, 4, 64);
            s += __shfl_xor(s, 8, 64);
            if (lr == 0) densc_l[t0 + reg] = s;
        }
    }
    __syncthreads();

    // phase 2b: Sc . V  (waves 0,1 only need tau<32)
    {
        int kmax = (w >= 2) ? 64 : 32;
        for (int k0 = 0; k0 < kmax; k0 += 32) {
            bf16x8 a = *(const bf16x8*)(sc + (16 * w + lr) * 64 + k0 + quad * 8);
#pragma unroll
            for (int tc = 0; tc < 4; tc++) {
                bf16x8 bb = *(const bf16x8*)(vT + (16 * tc + lr) * 64 + k0 + quad * 8);
                acc[tc] = __builtin_amdgcn_mfma_f32_16x16x32_bf16(a, bb, acc[tc], 0, 0, 0);
            }
        }
    }

    // epilogue: divide by den, write out
    {
        int t0 = 16 * w + 4 * quad;
        float inv[4];
#pragma unroll
        for (int reg = 0; reg < 4; reg++)
            inv[reg] = 1.0f / (den0_l[t0 + reg] + densc_l[t0 + reg]);
#pragma unroll
        for (int tc = 0; tc < 4; tc++)
#pragma unroll
            for (int reg = 0; reg < 4; reg++)
                out[((size_t)(b * L_ + l0 + t0 + reg) * H_ + h) * D_ + 16 * tc + lr] =
                    acc[tc][reg] * inv[reg];
    }
}

extern "C" void kernel_launch(void* const* d_in, const int* in_sizes, int n_in,
                              void* d_out, int out_size, void* d_ws, size_t ws_size,
                              hipStream_t stream) {
    const float* q = (const float*)d_in[0];
    const float* k = (const float*)d_in[1];
    const float* v = (const float*)d_in[2];
    const float* proj = (const float*)d_in[3];
    float* out = (float*)d_out;
    char* W = (char*)d_ws;

    // workspace layout (bytes)
    bf16* qp   = (bf16*)(W);                       //  33,554,432  [b][l][h][m]
    bf16* kp   = (bf16*)(W + 33554432ull);         //  33,554,432  [b][l][h][m]
    bf16* kpT  = (bf16*)(W + 67108864ull);         //  33,554,432  [b][h][m][l]
    bf16* vbT  = (bf16*)(W + 100663296ull);        //  16,777,216  [b][h][d][l]
    float* ktmp = (float*)(W + 117440512ull);      //  67,108,864  fp32 dd-diag
    bf16* S    = (bf16*)(W + 117440512ull);        //  alias over ktmp (33.5 MB)
    float* ds  = (float*)(W + 184549376ull);       //   1,048,576
    unsigned* mx = (unsigned*)(W + 185597952ull);  //   256

    hipLaunchKernelGGL(init_mx, dim3(1), dim3(64), 0, stream, mx);
    hipLaunchKernelGGL((feat_gemm<false>), dim3(2048), dim3(256), 0, stream,
                       k, proj, (void*)ktmp, mx);
    hipLaunchKernelGGL((feat_gemm<true>), dim3(2048), dim3(256), 0, stream,
                       q, proj, (void*)qp, (unsigned*)nullptr);
    hipLaunchKernelGGL(k_exp_t, dim3(2048), dim3(256), 0, stream, ktmp, mx, kp, kpT);
    hipLaunchKernelGGL(v_tr, dim3(2048), dim3(256), 0, stream, v, vbT);
    hipLaunchKernelGGL(chunk_mfma, dim3(2048), dim3(256), 0, stream, kpT, vbT, S, ds);
    hipLaunchKernelGGL(prefix_S, dim3(1024), dim3(256), 0, stream, (unsigned*)S);
    hipLaunchKernelGGL(prefix_D, dim3(64), dim3(128), 0, stream, ds);
    hipLaunchKernelGGL(attn_mfma, dim3(2048), dim3(256), 0, stream,
                       qp, kp, vbT, S, ds, out);
}

// Round 4
// 285.222 us; speedup vs baseline: 6.9296x; 1.0138x over previous
//
#include <hip/hip_runtime.h>
#include <math.h>

// Problem constants (match reference)
#define B_ 4
#define L_ 2048
#define H_ 16
#define D_ 64
#define M_ 128
#define TC_ 64              // chunk length
#define NC_ (L_ / TC_)      // 32 chunks
#define EPSK 1e-6f
#define DATA_SCALE 0.35355339059327379f  // 64^{-1/4}
#define RATIO 0.08838834764831845f       // 128^{-1/2}

typedef __bf16 bf16;
typedef bf16 bf16x4 __attribute__((ext_vector_type(4)));
typedef bf16 bf16x8 __attribute__((ext_vector_type(8)));
typedef float floatx4 __attribute__((ext_vector_type(4)));

__device__ __forceinline__ unsigned pk(bf16 a, bf16 b) {
    return (unsigned)__builtin_bit_cast(unsigned short, a) |
           ((unsigned)__builtin_bit_cast(unsigned short, b) << 16);
}
__device__ __forceinline__ void split2(float x, bf16& hi, bf16& lo) {
    hi = (bf16)x;
    lo = (bf16)(x - (float)hi);
}

// ---- order-preserving float<->uint for atomic max ----
__device__ __forceinline__ unsigned enc_f(float f) {
    unsigned u = __float_as_uint(f);
    return (u & 0x80000000u) ? ~u : (u | 0x80000000u);
}
__device__ __forceinline__ float dec_f(unsigned u) {
    unsigned b = (u & 0x80000000u) ? (u ^ 0x80000000u) : ~u;
    return __uint_as_float(b);
}

__global__ void init_mx(unsigned* __restrict__ mx) {
    if (threadIdx.x < B_ * H_) mx[threadIdx.x] = 0u;
}

// ---------------------------------------------------------------------------
// Feature map via MFMA with bf16 hi/lo split (fp32-accurate dd).
// Block = (b,h,c): 64 l-rows at fixed (b,h). dd[l][m] = sum_k a[l][k]p[m][k].
// MODE 0: k max pass   -> atomicMax raw dd per (b,h); no stores.
// MODE 1: k exp pass   -> kp[b,l,h,m] bf16 + kpT[b,h,m,l] bf16 (global max).
// MODE 2: q pass       -> qp[b,l,h,m] bf16 (per-row max).
// A/B tiles [row][k] padded to 72 elems: frag reads are 16B ds_read_b128,
// bank pattern (4*row+4*quad)%32 -> 2-way aliasing (free).
// ---------------------------------------------------------------------------
template <int MODE>
__global__ __launch_bounds__(256) void feat_mfma(const float* __restrict__ data,
                                                 const float* __restrict__ proj,
                                                 unsigned* __restrict__ mxk,
                                                 bf16* __restrict__ outp,
                                                 bf16* __restrict__ outT) {
    __shared__ __align__(16) bf16 ahi[64 * 72], alo[64 * 72];
    __shared__ __align__(16) bf16 phi[128 * 72], plo[128 * 72];
    __shared__ __align__(16) bf16 sc[64 * 130];
    __shared__ float diag_s[64];
    __shared__ float wred[4];

    int tid = threadIdx.x;
    int blk = blockIdx.x;
    int c = blk & 31, h = (blk >> 5) & 15, b = blk >> 9;
    int l0 = c * 64;

    // stage proj (128x64 fp32 -> hi/lo bf16), L2-resident after first blocks
    const float4* p4 = (const float4*)proj;
#pragma unroll
    for (int i = 0; i < 8; i++) {
        int ch = tid + 256 * i;          // 0..2047
        int m = ch >> 4, c4 = ch & 15;
        float4 x = p4[ch];
        bf16 h0, h1, h2, h3, l0_, l1, l2, l3;
        split2(x.x, h0, l0_); split2(x.y, h1, l1);
        split2(x.z, h2, l2);  split2(x.w, h3, l3);
        uint2 uh = {pk(h0, h1), pk(h2, h3)};
        uint2 ul = {pk(l0_, l1), pk(l2, l3)};
        *(uint2*)&phi[m * 72 + c4 * 4] = uh;
        *(uint2*)&plo[m * 72 + c4 * 4] = ul;
    }
    // stage data rows (64 x 64 fp32, strided by H*D) -> scaled hi/lo bf16
#pragma unroll
    for (int i = 0; i < 4; i++) {
        int ch = tid + 256 * i;          // 0..1023
        int row = ch >> 4, c4 = ch & 15;
        const float4* gp = (const float4*)(data +
            ((size_t)(b * L_ + l0 + row) * H_ + h) * D_) + c4;
        float4 x = *gp;
        float a0 = DATA_SCALE * x.x, a1 = DATA_SCALE * x.y;
        float a2 = DATA_SCALE * x.z, a3 = DATA_SCALE * x.w;
        bf16 h0, h1, h2, h3, l0_, l1, l2, l3;
        split2(a0, h0, l0_); split2(a1, h1, l1);
        split2(a2, h2, l2);  split2(a3, h3, l3);
        uint2 uh = {pk(h0, h1), pk(h2, h3)};
        uint2 ul = {pk(l0_, l1), pk(l2, l3)};
        *(uint2*)&ahi[row * 72 + c4 * 4] = uh;
        *(uint2*)&alo[row * 72 + c4 * 4] = ul;
        if (MODE != 0) {
            float ss = a0 * a0 + a1 * a1 + a2 * a2 + a3 * a3;
            ss += __shfl_xor(ss, 1, 64);
            ss += __shfl_xor(ss, 2, 64);
            ss += __shfl_xor(ss, 4, 64);
            ss += __shfl_xor(ss, 8, 64);
            if ((tid & 15) == 0) diag_s[row] = 0.5f * ss;
        }
    }
    __syncthreads();

    int w = tid >> 6, lane = tid & 63, lr = lane & 15, quad = lane >> 4;
    const bf16* abh = ahi + (16 * w + lr) * 72 + quad * 8;
    const bf16* abl = alo + (16 * w + lr) * 72 + quad * 8;

    floatx4 acc[8];
#pragma unroll
    for (int tc = 0; tc < 8; tc++) acc[tc] = (floatx4){0.f, 0.f, 0.f, 0.f};

#pragma unroll
    for (int k0 = 0; k0 < 64; k0 += 32) {
        bf16x8 ah = *(const bf16x8*)(abh + k0);
        bf16x8 al = *(const bf16x8*)(abl + k0);
#pragma unroll
        for (int tc = 0; tc < 8; tc++) {
            const bf16* bp = phi + (16 * tc + lr) * 72 + quad * 8 + k0;
            const bf16* bq = plo + (16 * tc + lr) * 72 + quad * 8 + k0;
            bf16x8 bh = *(const bf16x8*)bp;
            bf16x8 bl = *(const bf16x8*)bq;
            acc[tc] = __builtin_amdgcn_mfma_f32_16x16x32_bf16(ah, bh, acc[tc], 0, 0, 0);
            acc[tc] = __builtin_amdgcn_mfma_f32_16x16x32_bf16(al, bh, acc[tc], 0, 0, 0);
            acc[tc] = __builtin_amdgcn_mfma_f32_16x16x32_bf16(ah, bl, acc[tc], 0, 0, 0);
        }
    }

    if (MODE == 0) {
        // global max of raw dd over the whole tile
        float mm = acc[0][0];
#pragma unroll
        for (int tc = 0; tc < 8; tc++)
#pragma unroll
            for (int reg = 0; reg < 4; reg++) mm = fmaxf(mm, acc[tc][reg]);
#pragma unroll
        for (int off = 1; off < 64; off <<= 1) mm = fmaxf(mm, __shfl_xor(mm, off, 64));
        if (lane == 0) wred[w] = mm;
        __syncthreads();
        if (tid == 0) {
            float g = fmaxf(fmaxf(wred[0], wred[1]), fmaxf(wred[2], wred[3]));
            atomicMax(&mxk[b * H_ + h], enc_f(g));
        }
        return;
    }

    // epilogue: C rows t0..t0+3 (l), col 16tc+lr (m)
    int t0 = 16 * w + 4 * quad;
    float mxg = 0.f;
    if (MODE == 1) mxg = dec_f(mxk[b * H_ + h]);

    float rm[4];
    if (MODE == 2) {
#pragma unroll
        for (int reg = 0; reg < 4; reg++) {
            float m = acc[0][reg];
#pragma unroll
            for (int tc = 1; tc < 8; tc++) m = fmaxf(m, acc[tc][reg]);
            m = fmaxf(m, __shfl_xor(m, 1, 64));
            m = fmaxf(m, __shfl_xor(m, 2, 64));
            m = fmaxf(m, __shfl_xor(m, 4, 64));
            m = fmaxf(m, __shfl_xor(m, 8, 64));
            rm[reg] = m;
        }
    }

#pragma unroll
    for (int reg = 0; reg < 4; reg++) {
        float dg = diag_s[t0 + reg];
        float sh = (MODE == 1) ? (dg + mxg) : (dg + rm[reg]);
#pragma unroll
        for (int tc = 0; tc < 8; tc++) {
            float val = RATIO * (expf(acc[tc][reg] - sh) + EPSK);
            sc[(t0 + reg) * 130 + 16 * tc + lr] = (bf16)val;
        }
    }
    __syncthreads();

    // coalesced row-major store (kp / qp)
#pragma unroll
    for (int i = 0; i < 16; i++) {
        int e = tid + 256 * i;           // 4096 uints
        int row = e >> 6, mp = e & 63;
        unsigned u = pk(sc[row * 130 + 2 * mp], sc[row * 130 + 2 * mp + 1]);
        *(unsigned*)(outp + ((size_t)(b * L_ + l0 + row) * H_ + h) * M_ + 2 * mp) = u;
    }
    if (MODE == 1) {
        // transposed store kpT[b,h,m,l]
#pragma unroll
        for (int i = 0; i < 16; i++) {
            int e = tid + 256 * i;       // 4096 uints
            int m = e >> 5, t2 = (e & 31) * 2;
            unsigned u = pk(sc[t2 * 130 + m], sc[(t2 + 1) * 130 + m]);
            *(unsigned*)(outT + ((size_t)(b * H_ + h) * M_ + m) * L_ + l0 + t2) = u;
        }
    }
}

// ---------------------------------------------------------------------------
// V transpose: block = (b,h,c). v fp32 [b][l][h][d] -> vbT bf16 [b][h][d][l].
// ---------------------------------------------------------------------------
__global__ __launch_bounds__(256) void v_tr(const float* __restrict__ v,
                                            bf16* __restrict__ vbT) {
    __shared__ __align__(16) bf16 vt[64 * 66];
    int tid = threadIdx.x;
    int blk = blockIdx.x;
    int c = blk & 31, hh = (blk >> 5) & 15, b = blk >> 9;
#pragma unroll
    for (int i = 0; i < 4; i++) {
        int ch = tid + 256 * i;          // 1024 float4 chunks (64 rows x 16)
        int row = ch >> 4, c4 = ch & 15;
        size_t gb = ((size_t)(b * L_ + c * 64 + row) * H_ + hh) * D_;
        float4 x = *(const float4*)(v + gb + c4 * 4);
        unsigned* lp = (unsigned*)(vt + row * 66 + c4 * 4);
        lp[0] = pk((bf16)x.x, (bf16)x.y);
        lp[1] = pk((bf16)x.z, (bf16)x.w);
    }
    __syncthreads();
    size_t ob = (size_t)((b * H_ + hh) * D_) * (size_t)L_ + c * 64;
#pragma unroll
    for (int i = 0; i < 8; i++) {
        int e2 = tid + 256 * i;          // 2048 pairs
        int d = e2 >> 5, tau2 = (e2 & 31) * 2;
        *(unsigned*)(vbT + ob + (size_t)d * L_ + tau2) =
            pk(vt[tau2 * 66 + d], vt[(tau2 + 1) * 66 + d]);
    }
}

// ---------------------------------------------------------------------------
// Chunk sums via MFMA: S^T[d][m] = sum_tau v[tau][d]*kp[tau][m] (bf16 out),
// ds[m] = sum_tau kp[tau][m] (fp32). Block = (bh,c), 4 waves.
// ---------------------------------------------------------------------------
__global__ __launch_bounds__(256) void chunk_mfma(const bf16* __restrict__ kpT,
                                                  const bf16* __restrict__ vbT,
                                                  bf16* __restrict__ S,
                                                  float* __restrict__ ds) {
    __shared__ __align__(16) bf16 kT[128 * 64];   // [m][tau]
    __shared__ __align__(16) bf16 vT[64 * 64];    // [d][tau]
    int tid = threadIdx.x;
    int blk = blockIdx.x;
    int c = blk & 31, bh = blk >> 5;
    int l0 = c * 64;
#pragma unroll
    for (int i = 0; i < 4; i++) {
        int ch = tid + 256 * i;          // 1024 chunks (128 rows x 8)
        int m = ch >> 3, c8 = ch & 7;
        ((uint4*)kT)[ch] = ((const uint4*)kpT)[(((size_t)bh * M_ + m) * L_ + l0) / 8 + c8];
    }
#pragma unroll
    for (int i = 0; i < 2; i++) {
        int ch = tid + 256 * i;          // 512 chunks (64 rows x 8)
        int d = ch >> 3, c8 = ch & 7;
        ((uint4*)vT)[ch] = ((const uint4*)vbT)[(((size_t)bh * D_ + d) * L_ + l0) / 8 + c8];
    }
    __syncthreads();

    int w = tid >> 6, lane = tid & 63, lr = lane & 15, quad = lane >> 4;
    floatx4 acc[8];
#pragma unroll
    for (int tc = 0; tc < 8; tc++) acc[tc] = (floatx4){0.f, 0.f, 0.f, 0.f};
#pragma unroll
    for (int k0 = 0; k0 < 64; k0 += 32) {
        bf16x8 a = *(const bf16x8*)(vT + (16 * w + lr) * 64 + k0 + quad * 8);
#pragma unroll
        for (int tc = 0; tc < 8; tc++) {
            bf16x8 bb = *(const bf16x8*)(kT + (16 * tc + lr) * 64 + k0 + quad * 8);
            acc[tc] = __builtin_amdgcn_mfma_f32_16x16x32_bf16(a, bb, acc[tc], 0, 0, 0);
        }
    }
    size_t sb = (size_t)blk * (D_ * M_);
    int d0 = 16 * w + 4 * quad;
#pragma unroll
    for (int tc = 0; tc < 8; tc++)
#pragma unroll
        for (int reg = 0; reg < 4; reg++)
            S[sb + (size_t)(d0 + reg) * M_ + 16 * tc + lr] = (bf16)acc[tc][reg];

    // ds[m]: 2 threads per m, 32 taus each
    {
        int m = tid >> 1, half = tid & 1;
        const bf16x8* kr = (const bf16x8*)(kT + m * 64 + half * 32);
        float s = 0.f;
#pragma unroll
        for (int j = 0; j < 4; j++) {
            bf16x8 vv = kr[j];
#pragma unroll
            for (int e = 0; e < 8; e++) s += (float)vv[e];
        }
        s += __shfl_xor(s, 1, 64);
        if (!half) ds[(size_t)blk * M_ + m] = s;
    }
}

// Exclusive prefix over chunks, bf16 in place (fp32 carries), 2 elems/thread.
__global__ void prefix_S(unsigned* __restrict__ S) {
    int blk = blockIdx.x;
    int seg = blk & 15, bh = blk >> 4;
    int p = seg * 256 + threadIdx.x;            // 0..4095 uint pairs per chunk
    size_t base = (size_t)bh * NC_ * 4096 + p;
    float c0 = 0.f, c1 = 0.f;
    for (int c = 0; c < NC_; c++) {
        size_t a = base + (size_t)c * 4096;
        unsigned u = S[a];
        float f0 = (float)__builtin_bit_cast(bf16, (unsigned short)(u & 0xffffu));
        float f1 = (float)__builtin_bit_cast(bf16, (unsigned short)(u >> 16));
        S[a] = pk((bf16)c0, (bf16)c1);
        c0 += f0; c1 += f1;
    }
}

__global__ void prefix_D(float* __restrict__ ds) {
    int bh = blockIdx.x;
    int m = threadIdx.x;
    size_t base = (size_t)bh * NC_ * M_ + m;
    float carry = 0.f;
    for (int c = 0; c < NC_; c++) {
        size_t a = base + (size_t)c * M_;
        float val = ds[a];
        ds[a] = carry;
        carry += val;
    }
}

// ---------------------------------------------------------------------------
// Main attention via MFMA. Block = (bh,c), 4 waves; wave w owns t-rows
// 16w..16w+15. Phase1: Qp.S_prev (K=128). Phase2a: scores Qp.Kp^T (K=128),
// causal mask in C-regs, den row-reduce, bf16 round-trip through LDS.
// Phase2b: Sc.V (K=64). Out = acc/den.
// ---------------------------------------------------------------------------
__global__ __launch_bounds__(256) void attn_mfma(const bf16* __restrict__ qp,
                                                 const bf16* __restrict__ kp,
                                                 const bf16* __restrict__ vbT,
                                                 const bf16* __restrict__ Sp,
                                                 const float* __restrict__ dp,
                                                 float* __restrict__ out) {
    __shared__ __align__(16) bf16 qs[64 * 128];
    __shared__ __align__(16) bf16 ks[64 * 128];
    __shared__ __align__(16) bf16 spT[64 * 128];  // S_prev^T [d][m]
    __shared__ __align__(16) bf16 vT[64 * 64];    // [d][tau]
    __shared__ __align__(16) bf16 sc[64 * 64];    // masked scores [t][tau]
    __shared__ float dprevL[128];
    __shared__ float den0_l[64];
    __shared__ float densc_l[64];

    int tid = threadIdx.x;
    int blk = blockIdx.x;
    int c = blk & 31, bh = blk >> 5;
    int h = bh & 15, b = bh >> 4;
    int l0 = c * 64;

    // stage qs, ks (64x128 bf16 each)
#pragma unroll
    for (int i = 0; i < 4; i++) {
        int ch = tid + 256 * i;          // 1024 chunks (64 rows x 16)
        int row = ch >> 4, c8 = ch & 15;
        size_t gb = (((size_t)(b * L_ + l0 + row) * H_ + h) * M_) / 8;
        ((uint4*)qs)[ch] = ((const uint4*)qp)[gb + c8];
        ((uint4*)ks)[ch] = ((const uint4*)kp)[gb + c8];
    }
    // stage SpT (contiguous)
#pragma unroll
    for (int i = 0; i < 4; i++) {
        int ch = tid + 256 * i;
        ((uint4*)spT)[ch] = ((const uint4*)Sp)[(size_t)blk * 1024 + ch];
    }
    // stage vT + zero sc
    uint4 z; z.x = z.y = z.z = z.w = 0u;
#pragma unroll
    for (int i = 0; i < 2; i++) {
        int ch = tid + 256 * i;          // 512 chunks
        int d = ch >> 3, c8 = ch & 7;
        ((uint4*)vT)[ch] = ((const uint4*)vbT)[(((size_t)bh * D_ + d) * L_ + l0) / 8 + c8];
        ((uint4*)sc)[ch] = z;
    }
    if (tid < 128) dprevL[tid] = dp[(size_t)blk * M_ + tid];
    __syncthreads();

    // den0[t] = qp_t . dprev
    {
        int t = tid >> 2, p = tid & 3;
        const bf16* qrow = qs + t * 128 + p * 32;
        float s = 0.f;
#pragma unroll
        for (int i = 0; i < 32; i++) s += (float)qrow[i] * dprevL[p * 32 + i];
        s += __shfl_xor(s, 1, 64);
        s += __shfl_xor(s, 2, 64);
        if (p == 0) den0_l[t] = s;
    }

    int w = tid >> 6, lane = tid & 63, lr = lane & 15, quad = lane >> 4;
    const bf16* arow = qs + (16 * w + lr) * 128 + quad * 8;

    floatx4 acc[4];
#pragma unroll
    for (int tc = 0; tc < 4; tc++) acc[tc] = (floatx4){0.f, 0.f, 0.f, 0.f};

    // phase 1: Qp . S_prev
#pragma unroll
    for (int k0 = 0; k0 < 128; k0 += 32) {
        bf16x8 a = *(const bf16x8*)(arow + k0);
#pragma unroll
        for (int tc = 0; tc < 4; tc++) {
            bf16x8 bb = *(const bf16x8*)(spT + (16 * tc + lr) * 128 + k0 + quad * 8);
            acc[tc] = __builtin_amdgcn_mfma_f32_16x16x32_bf16(a, bb, acc[tc], 0, 0, 0);
        }
    }

    // phase 2a: scores (only tiles tc<=w needed; rest stays zero in sc)
    floatx4 acc2[4];
#pragma unroll
    for (int tc = 0; tc < 4; tc++) acc2[tc] = (floatx4){0.f, 0.f, 0.f, 0.f};
#pragma unroll
    for (int k0 = 0; k0 < 128; k0 += 32) {
        bf16x8 a = *(const bf16x8*)(arow + k0);
        for (int tc = 0; tc <= w; tc++) {
            bf16x8 bb = *(const bf16x8*)(ks + (16 * tc + lr) * 128 + k0 + quad * 8);
            acc2[tc] = __builtin_amdgcn_mfma_f32_16x16x32_bf16(a, bb, acc2[tc], 0, 0, 0);
        }
    }

    // mask + den partials + bf16 scores to LDS
    {
        float dsum[4] = {0.f, 0.f, 0.f, 0.f};
        int t0 = 16 * w + 4 * quad;
        for (int tc = 0; tc <= w; tc++) {
#pragma unroll
            for (int reg = 0; reg < 4; reg++) {
                int tg = t0 + reg, tau = 16 * tc + lr;
                float vv = acc2[tc][reg];
                if (tau > tg) vv = 0.f;
                dsum[reg] += vv;
                sc[tg * 64 + tau] = (bf16)vv;
            }
        }
#pragma unroll
        for (int reg = 0; reg < 4; reg++) {
            float s = dsum[reg];
            s += __shfl_xor(s, 1, 64);
            s += __shfl_xor(s, 2, 64);
            s += __shfl_xor(s, 4, 64);
            s += __shfl_xor(s, 8, 64);
            if (lr == 0) densc_l[t0 + reg] = s;
        }
    }
    __syncthreads();

    // phase 2b: Sc . V  (waves 0,1 only need tau<32)
    {
        int kmax = (w >= 2) ? 64 : 32;
        for (int k0 = 0; k0 < kmax; k0 += 32) {
            bf16x8 a = *(const bf16x8*)(sc + (16 * w + lr) * 64 + k0 + quad * 8);
#pragma unroll
            for (int tc = 0; tc < 4; tc++) {
                bf16x8 bb = *(const bf16x8*)(vT + (16 * tc + lr) * 64 + k0 + quad * 8);
                acc[tc] = __builtin_amdgcn_mfma_f32_16x16x32_bf16(a, bb, acc[tc], 0, 0, 0);
            }
        }
    }

    // epilogue: divide by den, write out
    {
        int t0 = 16 * w + 4 * quad;
        float inv[4];
#pragma unroll
        for (int reg = 0; reg < 4; reg++)
            inv[reg] = 1.0f / (den0_l[t0 + reg] + densc_l[t0 + reg]);
#pragma unroll
        for (int tc = 0; tc < 4; tc++)
#pragma unroll
            for (int reg = 0; reg < 4; reg++)
                out[((size_t)(b * L_ + l0 + t0 + reg) * H_ + h) * D_ + 16 * tc + lr] =
                    acc[tc][reg] * inv[reg];
    }
}

extern "C" void kernel_launch(void* const* d_in, const int* in_sizes, int n_in,
                              void* d_out, int out_size, void* d_ws, size_t ws_size,
                              hipStream_t stream) {
    const float* q = (const float*)d_in[0];
    const float* k = (const float*)d_in[1];
    const float* v = (const float*)d_in[2];
    const float* proj = (const float*)d_in[3];
    float* out = (float*)d_out;
    char* W = (char*)d_ws;

    // workspace layout (bytes)
    bf16* qp   = (bf16*)(W);                       //  33,554,432  [b][l][h][m]
    bf16* kp   = (bf16*)(W + 33554432ull);         //  33,554,432  [b][l][h][m]
    bf16* kpT  = (bf16*)(W + 67108864ull);         //  33,554,432  [b][h][m][l]
    bf16* vbT  = (bf16*)(W + 100663296ull);        //  16,777,216  [b][h][d][l]
    bf16* S    = (bf16*)(W + 117440512ull);        //  33,554,432  [bh,c][d][m]
    float* ds  = (float*)(W + 150994944ull);       //   1,048,576
    unsigned* mx = (unsigned*)(W + 152043520ull);  //   256

    hipLaunchKernelGGL(init_mx, dim3(1), dim3(64), 0, stream, mx);
    hipLaunchKernelGGL((feat_mfma<0>), dim3(2048), dim3(256), 0, stream,
                       k, proj, mx, (bf16*)nullptr, (bf16*)nullptr);
    hipLaunchKernelGGL((feat_mfma<1>), dim3(2048), dim3(256), 0, stream,
                       k, proj, mx, kp, kpT);
    hipLaunchKernelGGL((feat_mfma<2>), dim3(2048), dim3(256), 0, stream,
                       q, proj, mx, qp, (bf16*)nullptr);
    hipLaunchKernelGGL(v_tr, dim3(2048), dim3(256), 0, stream, v, vbT);
    hipLaunchKernelGGL(chunk_mfma, dim3(2048), dim3(256), 0, stream, kpT, vbT, S, ds);
    hipLaunchKernelGGL(prefix_S, dim3(1024), dim3(256), 0, stream, (unsigned*)S);
    hipLaunchKernelGGL(prefix_D, dim3(64), dim3(128), 0, stream, ds);
    hipLaunchKernelGGL(attn_mfma, dim3(2048), dim3(256), 0, stream,
                       qp, kp, vbT, S, ds, out);
}

// Round 5
// 273.412 us; speedup vs baseline: 7.2289x; 1.0432x over previous
//
#include <hip/hip_runtime.h>
#include <math.h>

// Problem constants (match reference)
#define B_ 4
#define L_ 2048
#define H_ 16
#define D_ 64
#define M_ 128
#define TC_ 64              // chunk length
#define NC_ (L_ / TC_)      // 32 chunks
#define EPSK 1e-6f
#define DATA_SCALE 0.35355339059327379f  // 64^{-1/4}
#define RATIO 0.08838834764831845f       // 128^{-1/2}

typedef __bf16 bf16;
typedef bf16 bf16x4 __attribute__((ext_vector_type(4)));
typedef bf16 bf16x8 __attribute__((ext_vector_type(8)));
typedef float floatx4 __attribute__((ext_vector_type(4)));

// padded row strides (bf16 elems): +8 keeps 16B alignment and shifts each row
// by 4 dwords -> a quarter-wave's 16 lr-lanes cover all 8 bank classes 2x (free)
#define PK128 136
#define PK64 72

__device__ __forceinline__ unsigned pk(bf16 a, bf16 b) {
    return (unsigned)__builtin_bit_cast(unsigned short, a) |
           ((unsigned)__builtin_bit_cast(unsigned short, b) << 16);
}
__device__ __forceinline__ void split2(float x, bf16& hi, bf16& lo) {
    hi = (bf16)x;
    lo = (bf16)(x - (float)hi);
}

// ---- order-preserving float<->uint for atomic max ----
__device__ __forceinline__ unsigned enc_f(float f) {
    unsigned u = __float_as_uint(f);
    return (u & 0x80000000u) ? ~u : (u | 0x80000000u);
}
__device__ __forceinline__ float dec_f(unsigned u) {
    unsigned b = (u & 0x80000000u) ? (u ^ 0x80000000u) : ~u;
    return __uint_as_float(b);
}

__global__ void init_mx(unsigned* __restrict__ mx) {
    if (threadIdx.x < B_ * H_) mx[threadIdx.x] = 0u;
}

// ---------------------------------------------------------------------------
// Feature map via MFMA with bf16 hi/lo split (fp32-accurate dd).
// Block = (b,h,c): 64 l-rows at fixed (b,h).
// MODE 0: k max pass -> atomicMax raw dd per (b,h).
// MODE 1: k exp pass -> kp + kpT. MODE 2: q pass -> qp (per-row max).
// ---------------------------------------------------------------------------
template <int MODE>
__global__ __launch_bounds__(256) void feat_mfma(const float* __restrict__ data,
                                                 const float* __restrict__ proj,
                                                 unsigned* __restrict__ mxk,
                                                 bf16* __restrict__ outp,
                                                 bf16* __restrict__ outT) {
    __shared__ __align__(16) bf16 ahi[64 * PK64], alo[64 * PK64];
    __shared__ __align__(16) bf16 phi[128 * PK64], plo[128 * PK64];
    __shared__ __align__(16) bf16 sc[64 * 130];
    __shared__ float diag_s[64];
    __shared__ float wred[4];

    int tid = threadIdx.x;
    int blk = blockIdx.x;
    int c = blk & 31, h = (blk >> 5) & 15, b = blk >> 9;
    int l0 = c * 64;

    const float4* p4 = (const float4*)proj;
#pragma unroll
    for (int i = 0; i < 8; i++) {
        int ch = tid + 256 * i;          // 0..2047
        int m = ch >> 4, c4 = ch & 15;
        float4 x = p4[ch];
        bf16 h0, h1, h2, h3, l0_, l1, l2, l3;
        split2(x.x, h0, l0_); split2(x.y, h1, l1);
        split2(x.z, h2, l2);  split2(x.w, h3, l3);
        uint2 uh = {pk(h0, h1), pk(h2, h3)};
        uint2 ul = {pk(l0_, l1), pk(l2, l3)};
        *(uint2*)&phi[m * PK64 + c4 * 4] = uh;
        *(uint2*)&plo[m * PK64 + c4 * 4] = ul;
    }
#pragma unroll
    for (int i = 0; i < 4; i++) {
        int ch = tid + 256 * i;          // 0..1023
        int row = ch >> 4, c4 = ch & 15;
        const float4* gp = (const float4*)(data +
            ((size_t)(b * L_ + l0 + row) * H_ + h) * D_) + c4;
        float4 x = *gp;
        float a0 = DATA_SCALE * x.x, a1 = DATA_SCALE * x.y;
        float a2 = DATA_SCALE * x.z, a3 = DATA_SCALE * x.w;
        bf16 h0, h1, h2, h3, l0_, l1, l2, l3;
        split2(a0, h0, l0_); split2(a1, h1, l1);
        split2(a2, h2, l2);  split2(a3, h3, l3);
        uint2 uh = {pk(h0, h1), pk(h2, h3)};
        uint2 ul = {pk(l0_, l1), pk(l2, l3)};
        *(uint2*)&ahi[row * PK64 + c4 * 4] = uh;
        *(uint2*)&alo[row * PK64 + c4 * 4] = ul;
        if (MODE != 0) {
            float ss = a0 * a0 + a1 * a1 + a2 * a2 + a3 * a3;
            ss += __shfl_xor(ss, 1, 64);
            ss += __shfl_xor(ss, 2, 64);
            ss += __shfl_xor(ss, 4, 64);
            ss += __shfl_xor(ss, 8, 64);
            if ((tid & 15) == 0) diag_s[row] = 0.5f * ss;
        }
    }
    __syncthreads();

    int w = tid >> 6, lane = tid & 63, lr = lane & 15, quad = lane >> 4;
    const bf16* abh = ahi + (16 * w + lr) * PK64 + quad * 8;
    const bf16* abl = alo + (16 * w + lr) * PK64 + quad * 8;

    floatx4 acc[8];
#pragma unroll
    for (int tc = 0; tc < 8; tc++) acc[tc] = (floatx4){0.f, 0.f, 0.f, 0.f};

#pragma unroll
    for (int k0 = 0; k0 < 64; k0 += 32) {
        bf16x8 ah = *(const bf16x8*)(abh + k0);
        bf16x8 al = *(const bf16x8*)(abl + k0);
#pragma unroll
        for (int tc = 0; tc < 8; tc++) {
            bf16x8 bh = *(const bf16x8*)(phi + (16 * tc + lr) * PK64 + quad * 8 + k0);
            bf16x8 bl = *(const bf16x8*)(plo + (16 * tc + lr) * PK64 + quad * 8 + k0);
            acc[tc] = __builtin_amdgcn_mfma_f32_16x16x32_bf16(ah, bh, acc[tc], 0, 0, 0);
            acc[tc] = __builtin_amdgcn_mfma_f32_16x16x32_bf16(al, bh, acc[tc], 0, 0, 0);
            acc[tc] = __builtin_amdgcn_mfma_f32_16x16x32_bf16(ah, bl, acc[tc], 0, 0, 0);
        }
    }

    if (MODE == 0) {
        float mm = acc[0][0];
#pragma unroll
        for (int tc = 0; tc < 8; tc++)
#pragma unroll
            for (int reg = 0; reg < 4; reg++) mm = fmaxf(mm, acc[tc][reg]);
#pragma unroll
        for (int off = 1; off < 64; off <<= 1) mm = fmaxf(mm, __shfl_xor(mm, off, 64));
        if (lane == 0) wred[w] = mm;
        __syncthreads();
        if (tid == 0) {
            float g = fmaxf(fmaxf(wred[0], wred[1]), fmaxf(wred[2], wred[3]));
            atomicMax(&mxk[b * H_ + h], enc_f(g));
        }
        return;
    }

    int t0 = 16 * w + 4 * quad;
    float mxg = 0.f;
    if (MODE == 1) mxg = dec_f(mxk[b * H_ + h]);

    float rm[4];
    if (MODE == 2) {
#pragma unroll
        for (int reg = 0; reg < 4; reg++) {
            float m = acc[0][reg];
#pragma unroll
            for (int tc = 1; tc < 8; tc++) m = fmaxf(m, acc[tc][reg]);
            m = fmaxf(m, __shfl_xor(m, 1, 64));
            m = fmaxf(m, __shfl_xor(m, 2, 64));
            m = fmaxf(m, __shfl_xor(m, 4, 64));
            m = fmaxf(m, __shfl_xor(m, 8, 64));
            rm[reg] = m;
        }
    }

#pragma unroll
    for (int reg = 0; reg < 4; reg++) {
        float dg = diag_s[t0 + reg];
        float sh = (MODE == 1) ? (dg + mxg) : (dg + rm[reg]);
#pragma unroll
        for (int tc = 0; tc < 8; tc++) {
            float val = RATIO * (expf(acc[tc][reg] - sh) + EPSK);
            sc[(t0 + reg) * 130 + 16 * tc + lr] = (bf16)val;
        }
    }
    __syncthreads();

#pragma unroll
    for (int i = 0; i < 16; i++) {
        int e = tid + 256 * i;           // 4096 uints
        int row = e >> 6, mp = e & 63;
        unsigned u = pk(sc[row * 130 + 2 * mp], sc[row * 130 + 2 * mp + 1]);
        *(unsigned*)(outp + ((size_t)(b * L_ + l0 + row) * H_ + h) * M_ + 2 * mp) = u;
    }
    if (MODE == 1) {
#pragma unroll
        for (int i = 0; i < 16; i++) {
            int e = tid + 256 * i;       // 4096 uints
            int m = e >> 5, t2 = (e & 31) * 2;
            unsigned u = pk(sc[t2 * 130 + m], sc[(t2 + 1) * 130 + m]);
            *(unsigned*)(outT + ((size_t)(b * H_ + h) * M_ + m) * L_ + l0 + t2) = u;
        }
    }
}

// ---------------------------------------------------------------------------
// V transpose: block = (b,h,c). v fp32 [b][l][h][d] -> vbT bf16 [b][h][d][l].
// ---------------------------------------------------------------------------
__global__ __launch_bounds__(256) void v_tr(const float* __restrict__ v,
                                            bf16* __restrict__ vbT) {
    __shared__ __align__(16) bf16 vt[64 * 66];
    int tid = threadIdx.x;
    int blk = blockIdx.x;
    int c = blk & 31, hh = (blk >> 5) & 15, b = blk >> 9;
#pragma unroll
    for (int i = 0; i < 4; i++) {
        int ch = tid + 256 * i;          // 1024 float4 chunks (64 rows x 16)
        int row = ch >> 4, c4 = ch & 15;
        size_t gb = ((size_t)(b * L_ + c * 64 + row) * H_ + hh) * D_;
        float4 x = *(const float4*)(v + gb + c4 * 4);
        unsigned* lp = (unsigned*)(vt + row * 66 + c4 * 4);
        lp[0] = pk((bf16)x.x, (bf16)x.y);
        lp[1] = pk((bf16)x.z, (bf16)x.w);
    }
    __syncthreads();
    size_t ob = (size_t)((b * H_ + hh) * D_) * (size_t)L_ + c * 64;
#pragma unroll
    for (int i = 0; i < 8; i++) {
        int e2 = tid + 256 * i;          // 2048 pairs
        int d = e2 >> 5, tau2 = (e2 & 31) * 2;
        *(unsigned*)(vbT + ob + (size_t)d * L_ + tau2) =
            pk(vt[tau2 * 66 + d], vt[(tau2 + 1) * 66 + d]);
    }
}

// ---------------------------------------------------------------------------
// Chunk sums via MFMA: S^T[d][m] = sum_tau v[tau][d]*kp[tau][m] (bf16 out,
// coalesced via LDS repack), ds[m] = sum_tau kp[tau][m] (fp32).
// ---------------------------------------------------------------------------
__global__ __launch_bounds__(256) void chunk_mfma(const bf16* __restrict__ kpT,
                                                  const bf16* __restrict__ vbT,
                                                  bf16* __restrict__ S,
                                                  float* __restrict__ ds) {
    __shared__ __align__(16) bf16 kT[128 * PK64];   // [m][tau] padded
    __shared__ __align__(16) bf16 vT[64 * PK64];    // [d][tau] padded
    int tid = threadIdx.x;
    int blk = blockIdx.x;
    int c = blk & 31, bh = blk >> 5;
    int l0 = c * 64;
#pragma unroll
    for (int i = 0; i < 4; i++) {
        int ch = tid + 256 * i;          // 1024 chunks (128 rows x 8)
        int m = ch >> 3, c8 = ch & 7;
        *(uint4*)(kT + m * PK64 + c8 * 8) =
            ((const uint4*)kpT)[(((size_t)bh * M_ + m) * L_ + l0) / 8 + c8];
    }
#pragma unroll
    for (int i = 0; i < 2; i++) {
        int ch = tid + 256 * i;          // 512 chunks (64 rows x 8)
        int d = ch >> 3, c8 = ch & 7;
        *(uint4*)(vT + d * PK64 + c8 * 8) =
            ((const uint4*)vbT)[(((size_t)bh * D_ + d) * L_ + l0) / 8 + c8];
    }
    __syncthreads();

    int w = tid >> 6, lane = tid & 63, lr = lane & 15, quad = lane >> 4;
    floatx4 acc[8];
#pragma unroll
    for (int tc = 0; tc < 8; tc++) acc[tc] = (floatx4){0.f, 0.f, 0.f, 0.f};
#pragma unroll
    for (int k0 = 0; k0 < 64; k0 += 32) {
        bf16x8 a = *(const bf16x8*)(vT + (16 * w + lr) * PK64 + k0 + quad * 8);
#pragma unroll
        for (int tc = 0; tc < 8; tc++) {
            bf16x8 bb = *(const bf16x8*)(kT + (16 * tc + lr) * PK64 + k0 + quad * 8);
            acc[tc] = __builtin_amdgcn_mfma_f32_16x16x32_bf16(a, bb, acc[tc], 0, 0, 0);
        }
    }

    // ds[m]: 2 threads per m, 32 taus each (reads kT before repack overwrites)
    float dsv = 0.f;
    {
        int m = tid >> 1, half = tid & 1;
        const bf16x8* kr = (const bf16x8*)(kT + m * PK64 + half * 32);
#pragma unroll
        for (int j = 0; j < 4; j++) {
            bf16x8 vv = kr[j];
#pragma unroll
            for (int e = 0; e < 8; e++) dsv += (float)vv[e];
        }
        dsv += __shfl_xor(dsv, 1, 64);
    }
    __syncthreads();

    // repack acc into kT area as flat [d][m] (64x128), then coalesced store
    bf16* scr = kT;
    int d0 = 16 * w + 4 * quad;
#pragma unroll
    for (int tc = 0; tc < 8; tc++)
#pragma unroll
        for (int reg = 0; reg < 4; reg++)
            scr[(d0 + reg) * 128 + 16 * tc + lr] = (bf16)acc[tc][reg];
    if ((tid & 1) == 0) ds[(size_t)blk * M_ + (tid >> 1)] = dsv;
    __syncthreads();
#pragma unroll
    for (int i = 0; i < 4; i++) {
        int e = tid + 256 * i;           // 1024 uint4
        ((uint4*)S)[(size_t)blk * 1024 + e] = ((const uint4*)scr)[e];
    }
}

// Exclusive prefix over chunks, bf16 in place (fp32 carries), 2 elems/thread.
__global__ void prefix_S(unsigned* __restrict__ S) {
    int blk = blockIdx.x;
    int seg = blk & 15, bh = blk >> 4;
    int p = seg * 256 + threadIdx.x;            // 0..4095 uint pairs per chunk
    size_t base = (size_t)bh * NC_ * 4096 + p;
    float c0 = 0.f, c1 = 0.f;
    for (int c = 0; c < NC_; c++) {
        size_t a = base + (size_t)c * 4096;
        unsigned u = S[a];
        float f0 = (float)__builtin_bit_cast(bf16, (unsigned short)(u & 0xffffu));
        float f1 = (float)__builtin_bit_cast(bf16, (unsigned short)(u >> 16));
        S[a] = pk((bf16)c0, (bf16)c1);
        c0 += f0; c1 += f1;
    }
}

__global__ void prefix_D(float* __restrict__ ds) {
    int bh = blockIdx.x;
    int m = threadIdx.x;
    size_t base = (size_t)bh * NC_ * M_ + m;
    float carry = 0.f;
    for (int c = 0; c < NC_; c++) {
        size_t a = base + (size_t)c * M_;
        float val = ds[a];
        ds[a] = carry;
        carry += val;
    }
}

// ---------------------------------------------------------------------------
// Main attention via MFMA. Block = (bh,c), 4 waves; wave w owns t-rows
// 16w..16w+15. Q A-frags live in registers (loaded from global, reused in
// phase1 & 2a). LDS arena: ks(64x136) | spT(64x136, sc aliases) | vT(64x72)
// = 44 KB -> 3 blocks/CU.
// ---------------------------------------------------------------------------
__global__ __launch_bounds__(256) void attn_mfma(const bf16* __restrict__ qp,
                                                 const bf16* __restrict__ kp,
                                                 const bf16* __restrict__ vbT,
                                                 const bf16* __restrict__ Sp,
                                                 const float* __restrict__ dp,
                                                 float* __restrict__ out) {
    __shared__ __align__(16) bf16 arena[64 * PK128 * 2 + 64 * PK64];
    bf16* ks  = arena;                    // 64 x 136
    bf16* spT = arena + 64 * PK128;       // 64 x 136 (S_prev^T [d][m])
    bf16* sc  = spT;                      // 64 x 72, aliases spT after phase1
    bf16* vT  = arena + 2 * 64 * PK128;   // 64 x 72   [d][tau]
    __shared__ float dprevL[128];
    __shared__ float den0_l[64];
    __shared__ float densc_l[64];

    int tid = threadIdx.x;
    int blk = blockIdx.x;
    int c = blk & 31, bh = blk >> 5;
    int h = bh & 15, b = bh >> 4;
    int l0 = c * 64;

    // stage ks (padded)
#pragma unroll
    for (int i = 0; i < 4; i++) {
        int ch = tid + 256 * i;          // 1024 chunks (64 rows x 16)
        int row = ch >> 4, c8 = ch & 15;
        size_t gb = (((size_t)(b * L_ + l0 + row) * H_ + h) * M_) / 8;
        *(uint4*)(ks + row * PK128 + c8 * 8) = ((const uint4*)kp)[gb + c8];
    }
    // stage spT (padded; global is contiguous [blk][d][m])
#pragma unroll
    for (int i = 0; i < 4; i++) {
        int ch = tid + 256 * i;
        int row = ch >> 4, c8 = ch & 15;
        *(uint4*)(spT + row * PK128 + c8 * 8) = ((const uint4*)Sp)[(size_t)blk * 1024 + ch];
    }
    // stage vT (padded)
#pragma unroll
    for (int i = 0; i < 2; i++) {
        int ch = tid + 256 * i;          // 512 chunks
        int d = ch >> 3, c8 = ch & 7;
        *(uint4*)(vT + d * PK64 + c8 * 8) =
            ((const uint4*)vbT)[(((size_t)bh * D_ + d) * L_ + l0) / 8 + c8];
    }
    if (tid < 128) dprevL[tid] = dp[(size_t)blk * M_ + tid];
    __syncthreads();

    // den0[t] = qp_t . dprev  (qp straight from global, vectorized)
    {
        int t = tid >> 2, p = tid & 3;
        const bf16* qrow = qp + ((size_t)(b * L_ + l0 + t) * H_ + h) * M_ + p * 32;
        float s = 0.f;
#pragma unroll
        for (int j = 0; j < 4; j++) {
            bf16x8 vv = *(const bf16x8*)(qrow + 8 * j);
#pragma unroll
            for (int e = 0; e < 8; e++) s += (float)vv[e] * dprevL[p * 32 + 8 * j + e];
        }
        s += __shfl_xor(s, 1, 64);
        s += __shfl_xor(s, 2, 64);
        if (p == 0) den0_l[t] = s;
    }

    int w = tid >> 6, lane = tid & 63, lr = lane & 15, quad = lane >> 4;

    // Q A-frags in registers, reused by phase1 + phase2a
    bf16x8 af[4];
    {
        const bf16* qb = qp + ((size_t)(b * L_ + l0 + 16 * w + lr) * H_ + h) * M_ + quad * 8;
#pragma unroll
        for (int k = 0; k < 4; k++) af[k] = *(const bf16x8*)(qb + 32 * k);
    }

    floatx4 acc[4];
#pragma unroll
    for (int tc = 0; tc < 4; tc++) acc[tc] = (floatx4){0.f, 0.f, 0.f, 0.f};

    // phase 1: Qp . S_prev (B rows = spT, padded stride)
#pragma unroll
    for (int ki = 0; ki < 4; ki++) {
#pragma unroll
        for (int tc = 0; tc < 4; tc++) {
            bf16x8 bb = *(const bf16x8*)(spT + (16 * tc + lr) * PK128 + 32 * ki + quad * 8);
            acc[tc] = __builtin_amdgcn_mfma_f32_16x16x32_bf16(af[ki], bb, acc[tc], 0, 0, 0);
        }
    }

    // phase 2a: scores (tiles tc<=w)
    floatx4 acc2[4];
#pragma unroll
    for (int tc = 0; tc < 4; tc++) acc2[tc] = (floatx4){0.f, 0.f, 0.f, 0.f};
#pragma unroll
    for (int ki = 0; ki < 4; ki++) {
        for (int tc = 0; tc <= w; tc++) {
            bf16x8 bb = *(const bf16x8*)(ks + (16 * tc + lr) * PK128 + 32 * ki + quad * 8);
            acc2[tc] = __builtin_amdgcn_mfma_f32_16x16x32_bf16(af[ki], bb, acc2[tc], 0, 0, 0);
        }
    }
    __syncthreads();   // all phase-1 spT reads done before sc (alias) is written

    // mask + den partials + bf16 scores to LDS (full 64 cols incl. zeros)
    {
        float dsum[4] = {0.f, 0.f, 0.f, 0.f};
        int t0 = 16 * w + 4 * quad;
#pragma unroll
        for (int tc = 0; tc < 4; tc++) {
#pragma unroll
            for (int reg = 0; reg < 4; reg++) {
                int tg = t0 + reg, tau = 16 * tc + lr;
                float vv = (tc <= w) ? acc2[tc][reg] : 0.f;
                if (tau > tg) vv = 0.f;
                dsum[reg] += vv;
                sc[tg * PK64 + tau] = (bf16)vv;
            }
        }
#pragma unroll
        for (int reg = 0; reg < 4; reg++) {
            float s = dsum[reg];
            s += __shfl_xor(s, 1, 64);
            s += __shfl_xor(s, 2, 64);
            s += __shfl_xor(s, 4, 64);
            s += __shfl_xor(s, 8, 64);
            if (lr == 0) densc_l[t0 + reg] = s;
        }
    }
    __syncthreads();

    // phase 2b: Sc . V  (waves 0,1 only need tau<32)
    {
        int kmax = (w >= 2) ? 64 : 32;
        for (int k0 = 0; k0 < kmax; k0 += 32) {
            bf16x8 a = *(const bf16x8*)(sc + (16 * w + lr) * PK64 + k0 + quad * 8);
#pragma unroll
            for (int tc = 0; tc < 4; tc++) {
                bf16x8 bb = *(const bf16x8*)(vT + (16 * tc + lr) * PK64 + k0 + quad * 8);
                acc[tc] = __builtin_amdgcn_mfma_f32_16x16x32_bf16(a, bb, acc[tc], 0, 0, 0);
            }
        }
    }

    // epilogue
    {
        int t0 = 16 * w + 4 * quad;
        float inv[4];
#pragma unroll
        for (int reg = 0; reg < 4; reg++)
            inv[reg] = 1.0f / (den0_l[t0 + reg] + densc_l[t0 + reg]);
#pragma unroll
        for (int tc = 0; tc < 4; tc++)
#pragma unroll
            for (int reg = 0; reg < 4; reg++)
                out[((size_t)(b * L_ + l0 + t0 + reg) * H_ + h) * D_ + 16 * tc + lr] =
                    acc[tc][reg] * inv[reg];
    }
}

extern "C" void kernel_launch(void* const* d_in, const int* in_sizes, int n_in,
                              void* d_out, int out_size, void* d_ws, size_t ws_size,
                              hipStream_t stream) {
    const float* q = (const float*)d_in[0];
    const float* k = (const float*)d_in[1];
    const float* v = (const float*)d_in[2];
    const float* proj = (const float*)d_in[3];
    float* out = (float*)d_out;
    char* W = (char*)d_ws;

    // workspace layout (bytes)
    bf16* qp   = (bf16*)(W);                       //  33,554,432  [b][l][h][m]
    bf16* kp   = (bf16*)(W + 33554432ull);         //  33,554,432  [b][l][h][m]
    bf16* kpT  = (bf16*)(W + 67108864ull);         //  33,554,432  [b][h][m][l]
    bf16* vbT  = (bf16*)(W + 100663296ull);        //  16,777,216  [b][h][d][l]
    bf16* S    = (bf16*)(W + 117440512ull);        //  33,554,432  [bh,c][d][m]
    float* ds  = (float*)(W + 150994944ull);       //   1,048,576
    unsigned* mx = (unsigned*)(W + 152043520ull);  //   256

    hipLaunchKernelGGL(init_mx, dim3(1), dim3(64), 0, stream, mx);
    hipLaunchKernelGGL((feat_mfma<0>), dim3(2048), dim3(256), 0, stream,
                       k, proj, mx, (bf16*)nullptr, (bf16*)nullptr);
    hipLaunchKernelGGL((feat_mfma<1>), dim3(2048), dim3(256), 0, stream,
                       k, proj, mx, kp, kpT);
    hipLaunchKernelGGL((feat_mfma<2>), dim3(2048), dim3(256), 0, stream,
                       q, proj, mx, qp, (bf16*)nullptr);
    hipLaunchKernelGGL(v_tr, dim3(2048), dim3(256), 0, stream, v, vbT);
    hipLaunchKernelGGL(chunk_mfma, dim3(2048), dim3(256), 0, stream, kpT, vbT, S, ds);
    hipLaunchKernelGGL(prefix_S, dim3(1024), dim3(256), 0, stream, (unsigned*)S);
    hipLaunchKernelGGL(prefix_D, dim3(64), dim3(128), 0, stream, ds);
    hipLaunchKernelGGL(attn_mfma, dim3(2048), dim3(256), 0, stream,
                       qp, kp, vbT, S, ds, out);
}